// Round 1
// baseline (1732.671 us; speedup 1.0000x reference)
//
#include <hip/hip_runtime.h>
#include <hip/hip_bf16.h>

typedef unsigned short u16;
typedef unsigned int   u32;

using bf16x8 = __attribute__((ext_vector_type(8))) short;
using f32x4  = __attribute__((ext_vector_type(4))) float;

constexpr int S = 4096, DIM = 4096, H = 32, HL = 8, D = 128;
constexpr int NQKV = (H + 2 * HL) * D;   // 6144
constexpr int TB = S / 8;                // 512 blocks of 8 tokens
constexpr int KL = 108;                  // 4 sink + 4 window + 100 heavy
constexpr float NEGF = -1e30f;
constexpr float SCALE = 0.08838834764831845f;  // 1/sqrt(128)

__device__ inline float bflo(u32 u) { return __builtin_bit_cast(float, u << 16); }
__device__ inline float bfhi(u32 u) { return __builtin_bit_cast(float, u & 0xFFFF0000u); }
__device__ inline u16 rne16(float f) {
  u32 b = __builtin_bit_cast(u32, f);
  return (u16)((b + 0x7FFFu + ((b >> 16) & 1u)) >> 16);
}
__device__ inline float bf2f(u16 h) { return __builtin_bit_cast(float, (u32)h << 16); }
__device__ inline u32 pk2(u16 a, u16 b) { return (u32)a | ((u32)b << 16); }

// async global->LDS, 16B per lane. LDS dest = wave-uniform base + lane*16.
__device__ __forceinline__ void gload16(const u16* g, u16* l) {
  __builtin_amdgcn_global_load_lds(
      (__attribute__((address_space(1))) void*)g,
      (__attribute__((address_space(3))) void*)l, 16, 0, 0);
}

// ================= conversion passes (memory-bound, one-shot) ===============
// f32 -> bf16 hi (rne) + bf16 lo (rne of residual). 8 elems/thread.
__global__ __launch_bounds__(256) void split_f32_kernel(
    const float* __restrict__ src, u16* __restrict__ hi, u16* __restrict__ lo) {
  const size_t i = ((size_t)blockIdx.x * 256 + threadIdx.x) * 8;
  float4 v0 = *(const float4*)(src + i);
  float4 v1 = *(const float4*)(src + i + 4);
  float f[8] = {v0.x, v0.y, v0.z, v0.w, v1.x, v1.y, v1.z, v1.w};
  u16 h[8], l[8];
#pragma unroll
  for (int j = 0; j < 8; ++j) {
    h[j] = rne16(f[j]);
    l[j] = rne16(f[j] - bf2f(h[j]));
  }
  uint4 ph, pl;
  ph.x = pk2(h[0], h[1]); ph.y = pk2(h[2], h[3]);
  ph.z = pk2(h[4], h[5]); ph.w = pk2(h[6], h[7]);
  pl.x = pk2(l[0], l[1]); pl.y = pk2(l[2], l[3]);
  pl.z = pk2(l[4], l[5]); pl.w = pk2(l[6], l[7]);
  *(uint4*)(hi + i) = ph;
  *(uint4*)(lo + i) = pl;
}

// wqkv f32 -> bf16 (all rows); K-head rows additionally emit the lo residual.
__global__ __launch_bounds__(256) void conv_wqkv_kernel(
    const float* __restrict__ src, u16* __restrict__ dst, u16* __restrict__ klo) {
  const size_t i = ((size_t)blockIdx.x * 256 + threadIdx.x) * 8;
  float4 v0 = *(const float4*)(src + i);
  float4 v1 = *(const float4*)(src + i + 4);
  float f[8] = {v0.x, v0.y, v0.z, v0.w, v1.x, v1.y, v1.z, v1.w};
  u16 h[8];
#pragma unroll
  for (int j = 0; j < 8; ++j) h[j] = rne16(f[j]);
  uint4 ph;
  ph.x = pk2(h[0], h[1]); ph.y = pk2(h[2], h[3]);
  ph.z = pk2(h[4], h[5]); ph.w = pk2(h[6], h[7]);
  *(uint4*)(dst + i) = ph;
  const int row = (int)(i >> 12);
  if (row >= H * D && row < (H + HL) * D) {
    u16 l[8];
#pragma unroll
    for (int j = 0; j < 8; ++j) l[j] = rne16(f[j] - bf2f(h[j]));
    uint4 pl;
    pl.x = pk2(l[0], l[1]); pl.y = pk2(l[2], l[3]);
    pl.z = pk2(l[4], l[5]); pl.w = pk2(l[6], l[7]);
    *(uint4*)(klo + (i - (size_t)(H * D) * DIM)) = pl;
  }
}

__global__ __launch_bounds__(256) void cast_bf16_kernel(
    const float* __restrict__ src, u16* __restrict__ dst) {
  const size_t i = ((size_t)blockIdx.x * 256 + threadIdx.x) * 8;
  float4 v0 = *(const float4*)(src + i);
  float4 v1 = *(const float4*)(src + i + 4);
  uint4 ph;
  ph.x = pk2(rne16(v0.x), rne16(v0.y));
  ph.y = pk2(rne16(v0.z), rne16(v0.w));
  ph.z = pk2(rne16(v1.x), rne16(v1.y));
  ph.w = pk2(rne16(v1.z), rne16(v1.w));
  *(uint4*)(dst + i) = ph;
}

// ============ bf16 GEMM, m97 structure: C[M,N] = A[M,K] * B[N,K]^T ==========
// 128x128 tile, BK=32, 4 waves, global_load_lds dwordx4 staging, linear LDS.
// Lane mapping: thread t stages A[m0 + t/4][k0 + (t%4)*8 .. +8); LDS byte
// offset t*16 == (t/4)*64 + (t%4)*16, i.e. row-major [128][32] with no pad.
template <bool OBF16, bool ACC>
__global__ __launch_bounds__(256) void gemm_bf16(
    const u16* __restrict__ A, const u16* __restrict__ B,
    void* __restrict__ Cp, int M, int N, int K, int lda, int ldb) {
  __shared__ u16 As[128 * 32];
  __shared__ u16 Bs[128 * 32];
  const int tid = threadIdx.x;
  const int lane = tid & 63;
  const int w = tid >> 6;
  const int wm = w >> 1, wn = w & 1;
  const int m0 = blockIdx.y * 128, n0 = blockIdx.x * 128;
  const int l15 = lane & 15, g = lane >> 4;
  const int srow = tid >> 2;          // 0..63
  const int scol = (tid & 3) * 8;     // u16 units: 0,8,16,24

  const u16* ga = A + (size_t)(m0 + srow) * lda + scol;
  const u16* gb = B + (size_t)(n0 + srow) * ldb + scol;
  const size_t a64 = (size_t)64 * lda;
  const size_t b64 = (size_t)64 * ldb;
  u16* lA = As + w * 512;             // 1024 B per wave
  u16* lB = Bs + w * 512;

  f32x4 acc[4][4];
#pragma unroll
  for (int i = 0; i < 4; ++i)
#pragma unroll
    for (int j = 0; j < 4; ++j) acc[i][j] = {0.f, 0.f, 0.f, 0.f};

  for (int k0 = 0; k0 < K; k0 += 32) {
    gload16(ga + k0, lA);             // A rows 0..63
    gload16(ga + k0 + a64, lA + 2048);// A rows 64..127
    gload16(gb + k0, lB);             // B rows 0..63
    gload16(gb + k0 + b64, lB + 2048);// B rows 64..127
    __syncthreads();                  // compiler emits vmcnt(0) drain here
    bf16x8 af[4], bfr[4];
#pragma unroll
    for (int i = 0; i < 4; ++i)
      af[i] = *(const bf16x8*)(As + (wm * 64 + i * 16 + l15) * 32 + g * 8);
#pragma unroll
    for (int j = 0; j < 4; ++j)
      bfr[j] = *(const bf16x8*)(Bs + (wn * 64 + j * 16 + l15) * 32 + g * 8);
#pragma unroll
    for (int i = 0; i < 4; ++i)
#pragma unroll
      for (int j = 0; j < 4; ++j)
        acc[i][j] = __builtin_amdgcn_mfma_f32_16x16x32_bf16(af[i], bfr[j], acc[i][j], 0, 0, 0);
    __syncthreads();
  }
  // C/D layout: col = lane&15, row = (lane>>4)*4 + reg   [verified m89/m91]
#pragma unroll
  for (int i = 0; i < 4; ++i)
#pragma unroll
    for (int j = 0; j < 4; ++j)
#pragma unroll
      for (int rg = 0; rg < 4; ++rg) {
        const int row = m0 + wm * 64 + i * 16 + g * 4 + rg;
        const int col = n0 + wn * 64 + j * 16 + l15;
        if constexpr (OBF16) {
          ((u16*)Cp)[(size_t)row * N + col] = rne16(acc[i][j][rg]);
        } else {
          float* C = (float*)Cp;
          const size_t idx = (size_t)row * N + col;
          C[idx] = ACC ? (C[idx] + acc[i][j][rg]) : acc[i][j][rg];
        }
      }
}

// ---------------- XC/XD: weighted token-sums of x (exact q_mean path) -------
__global__ __launch_bounds__(128) void xcd_kernel(
    const float* __restrict__ x, const float* __restrict__ freqs,
    float* __restrict__ XC, float* __restrict__ XD) {
  const int d = blockIdx.x * 128 + threadIdx.x;
  const int i0 = blockIdx.y * 32;
  const int s0 = blockIdx.z * 512;
  float accC[32], accD[32];
#pragma unroll
  for (int ii = 0; ii < 32; ++ii) { accC[ii] = 0.f; accD[ii] = 0.f; }
  for (int s = s0; s < s0 + 512; ++s) {
    const float xv = x[(size_t)s * DIM + d];
    const float* fr = freqs + (size_t)s * 128 + i0 * 2;  // block-uniform -> s_loads
#pragma unroll
    for (int ii = 0; ii < 32; ++ii) {
      accC[ii] += fr[2 * ii] * xv;
      accD[ii] += fr[2 * ii + 1] * xv;
    }
  }
#pragma unroll
  for (int ii = 0; ii < 32; ++ii) {
    atomicAdd(&XC[(size_t)(i0 + ii) * DIM + d], accC[ii]);
    atomicAdd(&XD[(size_t)(i0 + ii) * DIM + d], accD[ii]);
  }
}

// ---------------- M1/M2: per-q-row dots with XC/XD --------------------------
__global__ __launch_bounds__(256) void mrow_kernel(
    const float* __restrict__ wq, const float* __restrict__ XC,
    const float* __restrict__ XD, float* __restrict__ M1, float* __restrict__ M2) {
  const int r = blockIdx.x * 4 + (threadIdx.x >> 6);
  const int lane = threadIdx.x & 63;
  const int i = (r & 127) >> 1;
  const float* wr = wq + (size_t)r * DIM;
  const float* xc = XC + (size_t)i * DIM;
  const float* xd = XD + (size_t)i * DIM;
  float s1 = 0.f, s2 = 0.f;
  for (int k = lane; k < DIM; k += 64) {
    float wv = wr[k];
    s1 += wv * xc[k];
    s2 += wv * xd[k];
  }
#pragma unroll
  for (int off = 1; off < 64; off <<= 1) {
    s1 += __shfl_xor(s1, off, 64);
    s2 += __shfl_xor(s2, off, 64);
  }
  if (lane == 0) { M1[r] = s1; M2[r] = s2; }
}

// ---------------- RoPE on Q (bf16 in, bf16 out) -----------------------------
__global__ __launch_bounds__(256) void rope_q_kernel(
    const u16* __restrict__ qkvb, const float* __restrict__ freqs,
    u16* __restrict__ qb) {
  const int h = blockIdx.y;
  const int s0 = blockIdx.x * 64;
  const int tid = threadIdx.x;
  const int d = tid & 127, half = tid >> 7;
  for (int pp = half; pp < 64; pp += 2) {
    const int s = s0 + pp;
    u32 pr = *(const u32*)(qkvb + (size_t)s * NQKV + h * D + (d & ~1));
    float a = bflo(pr), b = bfhi(pr);
    float2 fc = *(const float2*)(freqs + (size_t)s * 128 + (d & ~1));
    float o = (d & 1) ? (b * fc.x + a * fc.y) : (a * fc.x - b * fc.y);
    qb[((size_t)h * S + s) * D + d] = rne16(o);
  }
}

// ---------------- RoPE on precise K + block means; V cast + transpose -------
__global__ __launch_bounds__(128) void rope_kv_kernel(
    const float* __restrict__ kf, const u16* __restrict__ qkvb,
    const float* __restrict__ freqs,
    u16* __restrict__ kb, u16* __restrict__ vbt, float* __restrict__ krep) {
  const int hl = blockIdx.y;
  const int t = blockIdx.x;  // token block 0..511
  const int d = threadIdx.x;
  float sum = 0.f;
  u16 vv[8];
#pragma unroll
  for (int pp = 0; pp < 8; ++pp) {
    const int s = t * 8 + pp;
    float2 kp = *(const float2*)(kf + (size_t)s * 1024 + hl * D + (d & ~1));
    float2 fc = *(const float2*)(freqs + (size_t)s * 128 + (d & ~1));
    float o = (d & 1) ? (kp.y * fc.x + kp.x * fc.y) : (kp.x * fc.x - kp.y * fc.y);
    kb[((size_t)hl * S + s) * D + d] = rne16(o);
    sum += o;
    vv[pp] = qkvb[(size_t)s * NQKV + (H + HL) * D + hl * D + d];  // already bf16
  }
  krep[((size_t)t * HL + hl) * D + d] = sum * 0.125f;
  uint4 pk;
  pk.x = pk2(vv[0], vv[1]);
  pk.y = pk2(vv[2], vv[3]);
  pk.z = pk2(vv[4], vv[5]);
  pk.w = pk2(vv[6], vv[7]);
  *(uint4*)(vbt + ((size_t)hl * D + d) * S + t * 8) = pk;
}

// ---------------- scores + top-100 selection per head -----------------------
__global__ __launch_bounds__(512) void topk_kernel(
    const float* __restrict__ M1, const float* __restrict__ M2,
    const float* __restrict__ krep, int* __restrict__ bidx) {
  const int h = blockIdx.x;
  const int t = threadIdx.x;  // block id 0..511
  __shared__ float qm[128];
  if (t < 128) {
    int r = h * 128 + t;
    float v = (t & 1) ? (M1[r] + M2[r - 1]) : (M1[r] - M2[r + 1]);
    qm[t] = v * (1.f / 4096.f);
  }
  __syncthreads();
  const float* kr = krep + ((size_t)t * HL + (h >> 2)) * 128;
  float s = 0.f;
#pragma unroll 8
  for (int d = 0; d < 128; ++d) s += qm[d] * kr[d];
  s *= SCALE;
  if (t < 4 || t >= 508) s = NEGF;  // sink + window masked out of top-k
  if (t < 4) {
    bidx[h * KL + t] = t;            // sink blocks 0..3
    bidx[h * KL + 4 + t] = 508 + t;  // window blocks 508..511
  }
  __shared__ float wv[8];
  __shared__ int wi[8];
  __shared__ int bestsh;
  for (int iter = 0; iter < 100; ++iter) {
    float v = s;
    int idx = t;
#pragma unroll
    for (int off = 1; off < 64; off <<= 1) {
      float ov = __shfl_xor(v, off, 64);
      int oi = __shfl_xor(idx, off, 64);
      if (ov > v || (ov == v && oi < idx)) { v = ov; idx = oi; }
    }
    if ((t & 63) == 0) { wv[t >> 6] = v; wi[t >> 6] = idx; }
    __syncthreads();
    if (t == 0) {
      float bv = wv[0];
      int bi = wi[0];
#pragma unroll
      for (int u = 1; u < 8; ++u)
        if (wv[u] > bv || (wv[u] == bv && wi[u] < bi)) { bv = wv[u]; bi = wi[u]; }
      bestsh = bi;
      bidx[h * KL + 8 + iter] = bi;
    }
    __syncthreads();
    if (t == bestsh) s = NEGF;
  }
}

// ---------------- MFMA flash attention over selected blocks -----------------
__global__ __launch_bounds__(256) void attn_mfma(
    const u16* __restrict__ qb, const u16* __restrict__ kb,
    const u16* __restrict__ vbt, const int* __restrict__ bidx,
    u16* __restrict__ attno) {
  __shared__ u16 Ks[32][136];   // 32 toks x 128 d (+8 pad)
  __shared__ u16 Vt[128][40];   // 128 d x 32 toks (+8 pad)
  __shared__ u16 Ps[4][16][40]; // per wave: 16 rows x 32 toks (+8 pad)
  const int h = blockIdx.y, hl = h >> 2;
  const int q0 = blockIdx.x * 64;
  const int tid = threadIdx.x;
  const int w = tid >> 6, lane = tid & 63;
  const int l15 = lane & 15, g = lane >> 4;

  bf16x8 qf[4];
  {
    const u16* qp = qb + ((size_t)h * S + q0 + w * 16 + l15) * D + g * 8;
#pragma unroll
    for (int c = 0; c < 4; ++c) qf[c] = *(const bf16x8*)(qp + c * 32);
  }
  f32x4 o[8];
#pragma unroll
  for (int c = 0; c < 8; ++c) o[c] = {0.f, 0.f, 0.f, 0.f};
  float mrow[4], lrow[4];
#pragma unroll
  for (int r = 0; r < 4; ++r) { mrow[r] = NEGF; lrow[r] = 0.f; }

  for (int step = 0; step < KL / 4; ++step) {
    const int b0 = bidx[h * KL + step * 4 + 0];
    const int b1 = bidx[h * KL + step * 4 + 1];
    const int b2 = bidx[h * KL + step * 4 + 2];
    const int b3 = bidx[h * KL + step * 4 + 3];
    {  // stage K: tok = tid>>3, seg = tid&7 (32B contiguous per thread)
      const int tok = tid >> 3, seg = tid & 7;
      const int blk = (tok < 8) ? b0 : (tok < 16) ? b1 : (tok < 24) ? b2 : b3;
      const u16* src = kb + ((size_t)hl * S + blk * 8 + (tok & 7)) * D + seg * 16;
      *(uint4*)&Ks[tok][seg * 16] = *(const uint4*)src;
      *(uint4*)&Ks[tok][seg * 16 + 8] = *(const uint4*)(src + 8);
    }
    {  // stage V^T: d = tid>>1, half = tid&1 (two 8-token runs)
      const int d = tid >> 1, hf = tid & 1;
      const int ba = hf ? b2 : b0, bb = hf ? b3 : b1;
      const u16* src = vbt + ((size_t)hl * D + d) * S;
      *(uint4*)&Vt[d][hf * 16] = *(const uint4*)(src + ba * 8);
      *(uint4*)&Vt[d][hf * 16 + 8] = *(const uint4*)(src + bb * 8);
    }
    __syncthreads();
    // QK^T: two 16x16 tiles (toks 0..15, 16..31)
    f32x4 sA = {0.f, 0.f, 0.f, 0.f}, sB = {0.f, 0.f, 0.f, 0.f};
#pragma unroll
    for (int c = 0; c < 4; ++c) {
      bf16x8 k0 = *(const bf16x8*)&Ks[l15][c * 32 + g * 8];
      bf16x8 k1 = *(const bf16x8*)&Ks[16 + l15][c * 32 + g * 8];
      sA = __builtin_amdgcn_mfma_f32_16x16x32_bf16(qf[c], k0, sA, 0, 0, 0);
      sB = __builtin_amdgcn_mfma_f32_16x16x32_bf16(qf[c], k1, sB, 0, 0, 0);
    }
    const int tgA = ((l15 < 8) ? b0 : b1) * 8 + (l15 & 7);
    const int tgB = ((l15 < 8) ? b2 : b3) * 8 + (l15 & 7);
    float pA[4], pB[4], alpha[4];
#pragma unroll
    for (int r = 0; r < 4; ++r) {
      const int sq = q0 + w * 16 + g * 4 + r;
      pA[r] = (tgA <= sq) ? sA[r] * SCALE : NEGF;
      pB[r] = (tgB <= sq) ? sB[r] * SCALE : NEGF;
      float mx = fmaxf(pA[r], pB[r]);
      mx = fmaxf(mx, __shfl_xor(mx, 1, 64));
      mx = fmaxf(mx, __shfl_xor(mx, 2, 64));
      mx = fmaxf(mx, __shfl_xor(mx, 4, 64));
      mx = fmaxf(mx, __shfl_xor(mx, 8, 64));
      const float mnew = fmaxf(mrow[r], mx);
      alpha[r] = __expf(mrow[r] - mnew);
      mrow[r] = mnew;
      pA[r] = __expf(pA[r] - mnew);
      pB[r] = __expf(pB[r] - mnew);
      float rs = pA[r] + pB[r];
      rs += __shfl_xor(rs, 1, 64);
      rs += __shfl_xor(rs, 2, 64);
      rs += __shfl_xor(rs, 4, 64);
      rs += __shfl_xor(rs, 8, 64);
      lrow[r] = lrow[r] * alpha[r] + rs;
    }
#pragma unroll
    for (int c = 0; c < 8; ++c) {
      o[c][0] *= alpha[0]; o[c][1] *= alpha[1];
      o[c][2] *= alpha[2]; o[c][3] *= alpha[3];
    }
    // P: C-layout -> LDS -> A-layout (within-wave, in-order LDS)
#pragma unroll
    for (int r = 0; r < 4; ++r) {
      Ps[w][g * 4 + r][l15] = rne16(pA[r]);
      Ps[w][g * 4 + r][16 + l15] = rne16(pB[r]);
    }
    bf16x8 pf = *(const bf16x8*)&Ps[w][l15][g * 8];
#pragma unroll
    for (int c = 0; c < 8; ++c) {
      bf16x8 vf = *(const bf16x8*)&Vt[c * 16 + l15][g * 8];
      o[c] = __builtin_amdgcn_mfma_f32_16x16x32_bf16(pf, vf, o[c], 0, 0, 0);
    }
    __syncthreads();
  }
  float inv[4];
#pragma unroll
  for (int r = 0; r < 4; ++r) inv[r] = 1.f / lrow[r];
#pragma unroll
  for (int c = 0; c < 8; ++c)
#pragma unroll
    for (int r = 0; r < 4; ++r)
      attno[(size_t)(q0 + w * 16 + g * 4 + r) * DIM + h * D + c * 16 + l15] =
          rne16(o[c][r] * inv[r]);
}

extern "C" void kernel_launch(void* const* d_in, const int* in_sizes, int n_in,
                              void* d_out, int out_size, void* d_ws, size_t ws_size,
                              hipStream_t stream) {
  const float* x     = (const float*)d_in[0];  // (1,4096,4096)
  const float* freqs = (const float*)d_in[1];  // (4096,64,2)
  const float* wqkv  = (const float*)d_in[2];  // (6144,4096)
  const float* wo    = (const float*)d_in[3];  // (4096,4096)
  float* out = (float*)d_out;                  // (1,4096,4096) f32

  char* p = (char*)d_ws;
  auto alloc = [&](size_t bytes) {
    char* r = p;
    p += (bytes + 255) & ~(size_t)255;
    return r;
  };
  u16*   xh   = (u16*)alloc((size_t)S * DIM * 2);        // 32 MB x hi (rne bf16)
  u16*   xl   = (u16*)alloc((size_t)S * DIM * 2);        // 32 MB x lo residual
  u16*   wqb  = (u16*)alloc((size_t)NQKV * DIM * 2);     // 48 MB wqkv bf16
  u16*   wkl  = (u16*)alloc((size_t)HL * D * DIM * 2);   //  8 MB K-head lo residual
  u16*   wob  = (u16*)alloc((size_t)DIM * DIM * 2);      // 32 MB wo bf16
  u16*   qkvb = (u16*)alloc((size_t)S * NQKV * 2);       // 48 MB bf16 qkv
  float* kf32 = (float*)alloc((size_t)S * HL * D * 4);   // 16 MB precise k
  u16*   qb   = (u16*)alloc((size_t)H * S * D * 2);      // 32 MB (H,S,D)
  u16*   kb   = (u16*)alloc((size_t)HL * S * D * 2);     //  8 MB (HL,S,D)
  u16*   vbt  = (u16*)alloc((size_t)HL * D * S * 2);     //  8 MB (HL,D,S)
  float* krep = (float*)alloc((size_t)TB * HL * D * 4);  //  2 MB
  float* XC   = (float*)alloc((size_t)64 * DIM * 4);     //  1 MB
  float* XD   = (float*)alloc((size_t)64 * DIM * 4);     //  1 MB
  float* M1   = (float*)alloc((size_t)H * D * 4);
  float* M2   = (float*)alloc((size_t)H * D * 4);
  int*   bidx = (int*)alloc((size_t)H * KL * 4);
  u16*   attno = (u16*)alloc((size_t)S * DIM * 2);       // 32 MB

  hipMemsetAsync(XC, 0, (size_t)64 * DIM * 4, stream);
  hipMemsetAsync(XD, 0, (size_t)64 * DIM * 4, stream);

  // ---- conversion passes (memory-bound) ----
  split_f32_kernel<<<(S * DIM) / 2048, 256, 0, stream>>>(x, xh, xl);
  conv_wqkv_kernel<<<(NQKV * DIM) / 2048, 256, 0, stream>>>(wqkv, wqb, wkl);
  cast_bf16_kernel<<<(DIM * DIM) / 2048, 256, 0, stream>>>(wo, wob);

  // ---- bf16 qkv (attention inputs): identical rne numerics to before ----
  gemm_bf16<true, false><<<dim3(NQKV / 128, S / 128), 256, 0, stream>>>(
      xh, wqb, qkvb, S, NQKV, DIM, DIM, DIM);

  // ---- precise K heads: (xh+xl)(wh+wl)^T, dropping the lo*lo term ----
  const u16* wkh = wqb + (size_t)H * D * DIM;  // K-head hi rows 4096..5119
  gemm_bf16<false, false><<<dim3((HL * D) / 128, S / 128), 256, 0, stream>>>(
      xh, wkh, kf32, S, HL * D, DIM, DIM, DIM);
  gemm_bf16<false, true><<<dim3((HL * D) / 128, S / 128), 256, 0, stream>>>(
      xh, wkl, kf32, S, HL * D, DIM, DIM, DIM);
  gemm_bf16<false, true><<<dim3((HL * D) / 128, S / 128), 256, 0, stream>>>(
      xl, wkh, kf32, S, HL * D, DIM, DIM, DIM);

  // ---- exact q_mean via rope linearity (f32 inputs, unchanged) ----
  xcd_kernel<<<dim3(32, 2, 8), 128, 0, stream>>>(x, freqs, XC, XD);
  mrow_kernel<<<1024, 256, 0, stream>>>(wqkv, XC, XD, M1, M2);
  rope_q_kernel<<<dim3(S / 64, H), 256, 0, stream>>>(qkvb, freqs, qb);
  rope_kv_kernel<<<dim3(TB, HL), 128, 0, stream>>>(kf32, qkvb, freqs, kb, vbt, krep);
  topk_kernel<<<H, 512, 0, stream>>>(M1, M2, krep, bidx);
  attn_mfma<<<dim3(S / 64, H), 256, 0, stream>>>(qb, kb, vbt, bidx, attno);
  gemm_bf16<false, false><<<dim3(DIM / 128, S / 128), 256, 0, stream>>>(
      attno, wob, out, S, DIM, DIM, DIM, DIM);
}

// Round 2
// 1465.280 us; speedup vs baseline: 1.1825x; 1.1825x over previous
//
#include <hip/hip_runtime.h>
#include <hip/hip_bf16.h>

typedef unsigned short u16;
typedef unsigned int   u32;

using bf16x8 = __attribute__((ext_vector_type(8))) short;
using f32x4  = __attribute__((ext_vector_type(4))) float;

constexpr int S = 4096, DIM = 4096, H = 32, HL = 8, D = 128;
constexpr int NQKV = (H + 2 * HL) * D;   // 6144
constexpr int TB = S / 8;                // 512 blocks of 8 tokens
constexpr int KL = 108;                  // 4 sink + 4 window + 100 heavy
constexpr float NEGF = -1e30f;
constexpr float SCALE = 0.08838834764831845f;  // 1/sqrt(128)

__device__ inline float bflo(u32 u) { return __builtin_bit_cast(float, u << 16); }
__device__ inline float bfhi(u32 u) { return __builtin_bit_cast(float, u & 0xFFFF0000u); }
__device__ inline u16 rne16(float f) {
  u32 b = __builtin_bit_cast(u32, f);
  return (u16)((b + 0x7FFFu + ((b >> 16) & 1u)) >> 16);
}
__device__ inline float bf2f(u16 h) { return __builtin_bit_cast(float, (u32)h << 16); }
__device__ inline u32 pk2(u16 a, u16 b) { return (u32)a | ((u32)b << 16); }

// async global->LDS, 16B per lane. LDS dest = wave-uniform base + lane*16.
__device__ __forceinline__ void gload16(const u16* g, u16* l) {
  __builtin_amdgcn_global_load_lds(
      (__attribute__((address_space(1))) void*)g,
      (__attribute__((address_space(3))) void*)l, 16, 0, 0);
}

// ================= conversion passes (memory-bound, one-shot) ===============
__global__ __launch_bounds__(256) void split_f32_kernel(
    const float* __restrict__ src, u16* __restrict__ hi, u16* __restrict__ lo) {
  const size_t i = ((size_t)blockIdx.x * 256 + threadIdx.x) * 8;
  float4 v0 = *(const float4*)(src + i);
  float4 v1 = *(const float4*)(src + i + 4);
  float f[8] = {v0.x, v0.y, v0.z, v0.w, v1.x, v1.y, v1.z, v1.w};
  u16 h[8], l[8];
#pragma unroll
  for (int j = 0; j < 8; ++j) {
    h[j] = rne16(f[j]);
    l[j] = rne16(f[j] - bf2f(h[j]));
  }
  uint4 ph, pl;
  ph.x = pk2(h[0], h[1]); ph.y = pk2(h[2], h[3]);
  ph.z = pk2(h[4], h[5]); ph.w = pk2(h[6], h[7]);
  pl.x = pk2(l[0], l[1]); pl.y = pk2(l[2], l[3]);
  pl.z = pk2(l[4], l[5]); pl.w = pk2(l[6], l[7]);
  *(uint4*)(hi + i) = ph;
  *(uint4*)(lo + i) = pl;
}

// wqkv f32 -> bf16 (all rows); K-head rows additionally emit the lo residual.
__global__ __launch_bounds__(256) void conv_wqkv_kernel(
    const float* __restrict__ src, u16* __restrict__ dst, u16* __restrict__ klo) {
  const size_t i = ((size_t)blockIdx.x * 256 + threadIdx.x) * 8;
  float4 v0 = *(const float4*)(src + i);
  float4 v1 = *(const float4*)(src + i + 4);
  float f[8] = {v0.x, v0.y, v0.z, v0.w, v1.x, v1.y, v1.z, v1.w};
  u16 h[8];
#pragma unroll
  for (int j = 0; j < 8; ++j) h[j] = rne16(f[j]);
  uint4 ph;
  ph.x = pk2(h[0], h[1]); ph.y = pk2(h[2], h[3]);
  ph.z = pk2(h[4], h[5]); ph.w = pk2(h[6], h[7]);
  *(uint4*)(dst + i) = ph;
  const int row = (int)(i >> 12);
  if (row >= H * D && row < (H + HL) * D) {
    u16 l[8];
#pragma unroll
    for (int j = 0; j < 8; ++j) l[j] = rne16(f[j] - bf2f(h[j]));
    uint4 pl;
    pl.x = pk2(l[0], l[1]); pl.y = pk2(l[2], l[3]);
    pl.z = pk2(l[4], l[5]); pl.w = pk2(l[6], l[7]);
    *(uint4*)(klo + (i - (size_t)(H * D) * DIM)) = pl;
  }
}

__global__ __launch_bounds__(256) void cast_bf16_kernel(
    const float* __restrict__ src, u16* __restrict__ dst) {
  const size_t i = ((size_t)blockIdx.x * 256 + threadIdx.x) * 8;
  float4 v0 = *(const float4*)(src + i);
  float4 v1 = *(const float4*)(src + i + 4);
  uint4 ph;
  ph.x = pk2(rne16(v0.x), rne16(v0.y));
  ph.y = pk2(rne16(v0.z), rne16(v0.w));
  ph.z = pk2(rne16(v1.x), rne16(v1.y));
  ph.w = pk2(rne16(v1.z), rne16(v1.w));
  *(uint4*)(dst + i) = ph;
}

// ============ bf16 GEMM, m97 structure: C[M,N] = A[M,K] * B[N,K]^T ==========
// 128x128 tile, BK=32, 4 waves, global_load_lds dwordx4 staging, linear LDS.
template <bool OBF16>
__global__ __launch_bounds__(256) void gemm_bf16(
    const u16* __restrict__ A, const u16* __restrict__ B,
    void* __restrict__ Cp, int M, int N, int K, int lda, int ldb, int ldc) {
  __shared__ u16 As[128 * 32];
  __shared__ u16 Bs[128 * 32];
  const int tid = threadIdx.x;
  const int lane = tid & 63;
  const int w = tid >> 6;
  const int wm = w >> 1, wn = w & 1;
  const int m0 = blockIdx.y * 128, n0 = blockIdx.x * 128;
  const int l15 = lane & 15, g = lane >> 4;
  const int srow = tid >> 2;          // 0..63
  const int scol = (tid & 3) * 8;     // u16 units: 0,8,16,24

  const u16* ga = A + (size_t)(m0 + srow) * lda + scol;
  const u16* gb = B + (size_t)(n0 + srow) * ldb + scol;
  const size_t a64 = (size_t)64 * lda;
  const size_t b64 = (size_t)64 * ldb;
  u16* lA = As + w * 512;             // 1024 B per wave
  u16* lB = Bs + w * 512;

  f32x4 acc[4][4];
#pragma unroll
  for (int i = 0; i < 4; ++i)
#pragma unroll
    for (int j = 0; j < 4; ++j) acc[i][j] = {0.f, 0.f, 0.f, 0.f};

  for (int k0 = 0; k0 < K; k0 += 32) {
    gload16(ga + k0, lA);             // A rows 0..63
    gload16(ga + k0 + a64, lA + 2048);// A rows 64..127
    gload16(gb + k0, lB);             // B rows 0..63
    gload16(gb + k0 + b64, lB + 2048);// B rows 64..127
    __syncthreads();
    bf16x8 af[4], bfr[4];
#pragma unroll
    for (int i = 0; i < 4; ++i)
      af[i] = *(const bf16x8*)(As + (wm * 64 + i * 16 + l15) * 32 + g * 8);
#pragma unroll
    for (int j = 0; j < 4; ++j)
      bfr[j] = *(const bf16x8*)(Bs + (wn * 64 + j * 16 + l15) * 32 + g * 8);
#pragma unroll
    for (int i = 0; i < 4; ++i)
#pragma unroll
      for (int j = 0; j < 4; ++j)
        acc[i][j] = __builtin_amdgcn_mfma_f32_16x16x32_bf16(af[i], bfr[j], acc[i][j], 0, 0, 0);
    __syncthreads();
  }
  // C/D layout: col = lane&15, row = (lane>>4)*4 + reg   [verified m89/m91]
#pragma unroll
  for (int i = 0; i < 4; ++i)
#pragma unroll
    for (int j = 0; j < 4; ++j)
#pragma unroll
      for (int rg = 0; rg < 4; ++rg) {
        const int row = m0 + wm * 64 + i * 16 + g * 4 + rg;
        const int col = n0 + wn * 64 + j * 16 + l15;
        if constexpr (OBF16)
          ((u16*)Cp)[(size_t)row * ldc + col] = rne16(acc[i][j][rg]);
        else
          ((float*)Cp)[(size_t)row * ldc + col] = acc[i][j][rg];
      }
}

// ============ fused 3-term split GEMM: C = Al*Bh^T + Ah*Bl^T + Ah*Bh^T ======
// Near-f32 precision for the K-head path. Tile 128(M)x64(N), BK=32, 4 waves;
// grid (N/64=16, M/128=32) = 512 blocks = 2/CU so barrier drains overlap.
__global__ __launch_bounds__(256) void gemm_k3(
    const u16* __restrict__ Ahg, const u16* __restrict__ Alg,
    const u16* __restrict__ Bhg, const u16* __restrict__ Blg,
    float* __restrict__ C, int M, int N, int K) {
  __shared__ u16 Ah[128 * 32];
  __shared__ u16 Al[128 * 32];
  __shared__ u16 Bh[64 * 32];
  __shared__ u16 Bl[64 * 32];
  const int tid = threadIdx.x;
  const int lane = tid & 63;
  const int w = tid >> 6;
  const int wm = w >> 1, wn = w & 1;   // wave tile: 64(M) x 32(N)
  const int m0 = blockIdx.y * 128, n0 = blockIdx.x * 64;
  const int l15 = lane & 15, g = lane >> 4;
  const int srow = tid >> 2;           // 0..63
  const int scol = (tid & 3) * 8;

  const u16* gah = Ahg + (size_t)(m0 + srow) * K + scol;
  const u16* gal = Alg + (size_t)(m0 + srow) * K + scol;
  const u16* gbh = Bhg + (size_t)(n0 + srow) * K + scol;
  const u16* gbl = Blg + (size_t)(n0 + srow) * K + scol;
  const size_t a64 = (size_t)64 * K;
  u16* lAh = Ah + w * 512;
  u16* lAl = Al + w * 512;
  u16* lBh = Bh + w * 512;
  u16* lBl = Bl + w * 512;

  f32x4 acc[4][2];
#pragma unroll
  for (int i = 0; i < 4; ++i)
#pragma unroll
    for (int j = 0; j < 2; ++j) acc[i][j] = {0.f, 0.f, 0.f, 0.f};

  for (int k0 = 0; k0 < K; k0 += 32) {
    gload16(gah + k0, lAh);
    gload16(gah + k0 + a64, lAh + 2048);
    gload16(gal + k0, lAl);
    gload16(gal + k0 + a64, lAl + 2048);
    gload16(gbh + k0, lBh);
    gload16(gbl + k0, lBl);
    __syncthreads();
    bf16x8 fah[4], fal[4], fbh[2], fbl[2];
#pragma unroll
    for (int i = 0; i < 4; ++i) {
      fah[i] = *(const bf16x8*)(Ah + (wm * 64 + i * 16 + l15) * 32 + g * 8);
      fal[i] = *(const bf16x8*)(Al + (wm * 64 + i * 16 + l15) * 32 + g * 8);
    }
#pragma unroll
    for (int j = 0; j < 2; ++j) {
      fbh[j] = *(const bf16x8*)(Bh + (wn * 32 + j * 16 + l15) * 32 + g * 8);
      fbl[j] = *(const bf16x8*)(Bl + (wn * 32 + j * 16 + l15) * 32 + g * 8);
    }
#pragma unroll
    for (int i = 0; i < 4; ++i)
#pragma unroll
      for (int j = 0; j < 2; ++j) {
        acc[i][j] = __builtin_amdgcn_mfma_f32_16x16x32_bf16(fal[i], fbh[j], acc[i][j], 0, 0, 0);
        acc[i][j] = __builtin_amdgcn_mfma_f32_16x16x32_bf16(fah[i], fbl[j], acc[i][j], 0, 0, 0);
        acc[i][j] = __builtin_amdgcn_mfma_f32_16x16x32_bf16(fah[i], fbh[j], acc[i][j], 0, 0, 0);
      }
    __syncthreads();
  }
#pragma unroll
  for (int i = 0; i < 4; ++i)
#pragma unroll
    for (int j = 0; j < 2; ++j)
#pragma unroll
      for (int rg = 0; rg < 4; ++rg) {
        const int row = m0 + wm * 64 + i * 16 + g * 4 + rg;
        const int col = n0 + wn * 32 + j * 16 + l15;
        C[(size_t)row * N + col] = acc[i][j][rg];
      }
}

// ---------------- XC/XD: weighted token-sums of x (exact q_mean path) -------
__global__ __launch_bounds__(128) void xcd_kernel(
    const float* __restrict__ x, const float* __restrict__ freqs,
    float* __restrict__ XC, float* __restrict__ XD) {
  const int d = blockIdx.x * 128 + threadIdx.x;
  const int i0 = blockIdx.y * 32;
  const int s0 = blockIdx.z * 128;
  float accC[32], accD[32];
#pragma unroll
  for (int ii = 0; ii < 32; ++ii) { accC[ii] = 0.f; accD[ii] = 0.f; }
  for (int s = s0; s < s0 + 128; ++s) {
    const float xv = x[(size_t)s * DIM + d];
    const float* fr = freqs + (size_t)s * 128 + i0 * 2;  // block-uniform -> s_loads
#pragma unroll
    for (int ii = 0; ii < 32; ++ii) {
      accC[ii] += fr[2 * ii] * xv;
      accD[ii] += fr[2 * ii + 1] * xv;
    }
  }
#pragma unroll
  for (int ii = 0; ii < 32; ++ii) {
    atomicAdd(&XC[(size_t)(i0 + ii) * DIM + d], accC[ii]);
    atomicAdd(&XD[(size_t)(i0 + ii) * DIM + d], accD[ii]);
  }
}

// ---------------- M1/M2: per-q-row dots with XC/XD --------------------------
__global__ __launch_bounds__(256) void mrow_kernel(
    const float* __restrict__ wq, const float* __restrict__ XC,
    const float* __restrict__ XD, float* __restrict__ M1, float* __restrict__ M2) {
  const int r = blockIdx.x * 4 + (threadIdx.x >> 6);
  const int lane = threadIdx.x & 63;
  const int i = (r & 127) >> 1;
  const float* wr = wq + (size_t)r * DIM;
  const float* xc = XC + (size_t)i * DIM;
  const float* xd = XD + (size_t)i * DIM;
  float s1 = 0.f, s2 = 0.f;
  for (int k = lane; k < DIM; k += 64) {
    float wv = wr[k];
    s1 += wv * xc[k];
    s2 += wv * xd[k];
  }
#pragma unroll
  for (int off = 1; off < 64; off <<= 1) {
    s1 += __shfl_xor(s1, off, 64);
    s2 += __shfl_xor(s2, off, 64);
  }
  if (lane == 0) { M1[r] = s1; M2[r] = s2; }
}

// ---------------- RoPE on Q (bf16 in, bf16 out) -----------------------------
__global__ __launch_bounds__(256) void rope_q_kernel(
    const u16* __restrict__ qkvb, const float* __restrict__ freqs,
    u16* __restrict__ qb) {
  const int h = blockIdx.y;
  const int s0 = blockIdx.x * 64;
  const int tid = threadIdx.x;
  const int d = tid & 127, half = tid >> 7;
  for (int pp = half; pp < 64; pp += 2) {
    const int s = s0 + pp;
    u32 pr = *(const u32*)(qkvb + (size_t)s * NQKV + h * D + (d & ~1));
    float a = bflo(pr), b = bfhi(pr);
    float2 fc = *(const float2*)(freqs + (size_t)s * 128 + (d & ~1));
    float o = (d & 1) ? (b * fc.x + a * fc.y) : (a * fc.x - b * fc.y);
    qb[((size_t)h * S + s) * D + d] = rne16(o);
  }
}

// ---------------- RoPE on precise K + block means; V cast + transpose -------
__global__ __launch_bounds__(128) void rope_kv_kernel(
    const float* __restrict__ kf, const u16* __restrict__ qkvb,
    const float* __restrict__ freqs,
    u16* __restrict__ kb, u16* __restrict__ vbt, float* __restrict__ krep) {
  const int hl = blockIdx.y;
  const int t = blockIdx.x;  // token block 0..511
  const int d = threadIdx.x;
  float sum = 0.f;
  u16 vv[8];
#pragma unroll
  for (int pp = 0; pp < 8; ++pp) {
    const int s = t * 8 + pp;
    float2 kp = *(const float2*)(kf + (size_t)s * 1024 + hl * D + (d & ~1));
    float2 fc = *(const float2*)(freqs + (size_t)s * 128 + (d & ~1));
    float o = (d & 1) ? (kp.y * fc.x + kp.x * fc.y) : (kp.x * fc.x - kp.y * fc.y);
    kb[((size_t)hl * S + s) * D + d] = rne16(o);
    sum += o;
    vv[pp] = qkvb[(size_t)s * NQKV + (H + HL) * D + hl * D + d];  // already bf16
  }
  krep[((size_t)t * HL + hl) * D + d] = sum * 0.125f;
  uint4 pk;
  pk.x = pk2(vv[0], vv[1]);
  pk.y = pk2(vv[2], vv[3]);
  pk.z = pk2(vv[4], vv[5]);
  pk.w = pk2(vv[6], vv[7]);
  *(uint4*)(vbt + ((size_t)hl * D + d) * S + t * 8) = pk;
}

// ---------------- scores + top-100 selection per head -----------------------
__global__ __launch_bounds__(512) void topk_kernel(
    const float* __restrict__ M1, const float* __restrict__ M2,
    const float* __restrict__ krep, int* __restrict__ bidx) {
  const int h = blockIdx.x;
  const int t = threadIdx.x;  // block id 0..511
  __shared__ float qm[128];
  if (t < 128) {
    int r = h * 128 + t;
    float v = (t & 1) ? (M1[r] + M2[r - 1]) : (M1[r] - M2[r + 1]);
    qm[t] = v * (1.f / 4096.f);
  }
  __syncthreads();
  const float* kr = krep + ((size_t)t * HL + (h >> 2)) * 128;
  float s = 0.f;
#pragma unroll 8
  for (int d = 0; d < 128; ++d) s += qm[d] * kr[d];
  s *= SCALE;
  if (t < 4 || t >= 508) s = NEGF;  // sink + window masked out of top-k
  if (t < 4) {
    bidx[h * KL + t] = t;            // sink blocks 0..3
    bidx[h * KL + 4 + t] = 508 + t;  // window blocks 508..511
  }
  __shared__ float wv[8];
  __shared__ int wi[8];
  __shared__ int bestsh;
  for (int iter = 0; iter < 100; ++iter) {
    float v = s;
    int idx = t;
#pragma unroll
    for (int off = 1; off < 64; off <<= 1) {
      float ov = __shfl_xor(v, off, 64);
      int oi = __shfl_xor(idx, off, 64);
      if (ov > v || (ov == v && oi < idx)) { v = ov; idx = oi; }
    }
    if ((t & 63) == 0) { wv[t >> 6] = v; wi[t >> 6] = idx; }
    __syncthreads();
    if (t == 0) {
      float bv = wv[0];
      int bi = wi[0];
#pragma unroll
      for (int u = 1; u < 8; ++u)
        if (wv[u] > bv || (wv[u] == bv && wi[u] < bi)) { bv = wv[u]; bi = wi[u]; }
      bestsh = bi;
      bidx[h * KL + 8 + iter] = bi;
    }
    __syncthreads();
    if (t == bestsh) s = NEGF;
  }
}

// ---------------- MFMA flash attention over selected blocks -----------------
__global__ __launch_bounds__(256) void attn_mfma(
    const u16* __restrict__ qb, const u16* __restrict__ kb,
    const u16* __restrict__ vbt, const int* __restrict__ bidx,
    u16* __restrict__ attno) {
  __shared__ u16 Ks[32][136];   // 32 toks x 128 d (+8 pad)
  __shared__ u16 Vt[128][40];   // 128 d x 32 toks (+8 pad)
  __shared__ u16 Ps[4][16][40]; // per wave: 16 rows x 32 toks (+8 pad)
  const int h = blockIdx.y, hl = h >> 2;
  const int q0 = blockIdx.x * 64;
  const int tid = threadIdx.x;
  const int w = tid >> 6, lane = tid & 63;
  const int l15 = lane & 15, g = lane >> 4;

  bf16x8 qf[4];
  {
    const u16* qp = qb + ((size_t)h * S + q0 + w * 16 + l15) * D + g * 8;
#pragma unroll
    for (int c = 0; c < 4; ++c) qf[c] = *(const bf16x8*)(qp + c * 32);
  }
  f32x4 o[8];
#pragma unroll
  for (int c = 0; c < 8; ++c) o[c] = {0.f, 0.f, 0.f, 0.f};
  float mrow[4], lrow[4];
#pragma unroll
  for (int r = 0; r < 4; ++r) { mrow[r] = NEGF; lrow[r] = 0.f; }

  for (int step = 0; step < KL / 4; ++step) {
    const int b0 = bidx[h * KL + step * 4 + 0];
    const int b1 = bidx[h * KL + step * 4 + 1];
    const int b2 = bidx[h * KL + step * 4 + 2];
    const int b3 = bidx[h * KL + step * 4 + 3];
    {  // stage K: tok = tid>>3, seg = tid&7 (32B contiguous per thread)
      const int tok = tid >> 3, seg = tid & 7;
      const int blk = (tok < 8) ? b0 : (tok < 16) ? b1 : (tok < 24) ? b2 : b3;
      const u16* src = kb + ((size_t)hl * S + blk * 8 + (tok & 7)) * D + seg * 16;
      *(uint4*)&Ks[tok][seg * 16] = *(const uint4*)src;
      *(uint4*)&Ks[tok][seg * 16 + 8] = *(const uint4*)(src + 8);
    }
    {  // stage V^T: d = tid>>1, half = tid&1 (two 8-token runs)
      const int d = tid >> 1, hf = tid & 1;
      const int ba = hf ? b2 : b0, bb = hf ? b3 : b1;
      const u16* src = vbt + ((size_t)hl * D + d) * S;
      *(uint4*)&Vt[d][hf * 16] = *(const uint4*)(src + ba * 8);
      *(uint4*)&Vt[d][hf * 16 + 8] = *(const uint4*)(src + bb * 8);
    }
    __syncthreads();
    // QK^T: two 16x16 tiles (toks 0..15, 16..31)
    f32x4 sA = {0.f, 0.f, 0.f, 0.f}, sB = {0.f, 0.f, 0.f, 0.f};
#pragma unroll
    for (int c = 0; c < 4; ++c) {
      bf16x8 k0 = *(const bf16x8*)&Ks[l15][c * 32 + g * 8];
      bf16x8 k1 = *(const bf16x8*)&Ks[16 + l15][c * 32 + g * 8];
      sA = __builtin_amdgcn_mfma_f32_16x16x32_bf16(qf[c], k0, sA, 0, 0, 0);
      sB = __builtin_amdgcn_mfma_f32_16x16x32_bf16(qf[c], k1, sB, 0, 0, 0);
    }
    const int tgA = ((l15 < 8) ? b0 : b1) * 8 + (l15 & 7);
    const int tgB = ((l15 < 8) ? b2 : b3) * 8 + (l15 & 7);
    float pA[4], pB[4], alpha[4];
#pragma unroll
    for (int r = 0; r < 4; ++r) {
      const int sq = q0 + w * 16 + g * 4 + r;
      pA[r] = (tgA <= sq) ? sA[r] * SCALE : NEGF;
      pB[r] = (tgB <= sq) ? sB[r] * SCALE : NEGF;
      float mx = fmaxf(pA[r], pB[r]);
      mx = fmaxf(mx, __shfl_xor(mx, 1, 64));
      mx = fmaxf(mx, __shfl_xor(mx, 2, 64));
      mx = fmaxf(mx, __shfl_xor(mx, 4, 64));
      mx = fmaxf(mx, __shfl_xor(mx, 8, 64));
      const float mnew = fmaxf(mrow[r], mx);
      alpha[r] = __expf(mrow[r] - mnew);
      mrow[r] = mnew;
      pA[r] = __expf(pA[r] - mnew);
      pB[r] = __expf(pB[r] - mnew);
      float rs = pA[r] + pB[r];
      rs += __shfl_xor(rs, 1, 64);
      rs += __shfl_xor(rs, 2, 64);
      rs += __shfl_xor(rs, 4, 64);
      rs += __shfl_xor(rs, 8, 64);
      lrow[r] = lrow[r] * alpha[r] + rs;
    }
#pragma unroll
    for (int c = 0; c < 8; ++c) {
      o[c][0] *= alpha[0]; o[c][1] *= alpha[1];
      o[c][2] *= alpha[2]; o[c][3] *= alpha[3];
    }
    // P: C-layout -> LDS -> A-layout (within-wave, in-order LDS)
#pragma unroll
    for (int r = 0; r < 4; ++r) {
      Ps[w][g * 4 + r][l15] = rne16(pA[r]);
      Ps[w][g * 4 + r][16 + l15] = rne16(pB[r]);
    }
    bf16x8 pf = *(const bf16x8*)&Ps[w][l15][g * 8];
#pragma unroll
    for (int c = 0; c < 8; ++c) {
      bf16x8 vf = *(const bf16x8*)&Vt[c * 16 + l15][g * 8];
      o[c] = __builtin_amdgcn_mfma_f32_16x16x32_bf16(pf, vf, o[c], 0, 0, 0);
    }
    __syncthreads();
  }
  float inv[4];
#pragma unroll
  for (int r = 0; r < 4; ++r) inv[r] = 1.f / lrow[r];
#pragma unroll
  for (int c = 0; c < 8; ++c)
#pragma unroll
    for (int r = 0; r < 4; ++r)
      attno[(size_t)(q0 + w * 16 + g * 4 + r) * DIM + h * D + c * 16 + l15] =
          rne16(o[c][r] * inv[r]);
}

extern "C" void kernel_launch(void* const* d_in, const int* in_sizes, int n_in,
                              void* d_out, int out_size, void* d_ws, size_t ws_size,
                              hipStream_t stream) {
  const float* x     = (const float*)d_in[0];  // (1,4096,4096)
  const float* freqs = (const float*)d_in[1];  // (4096,64,2)
  const float* wqkv  = (const float*)d_in[2];  // (6144,4096)
  const float* wo    = (const float*)d_in[3];  // (4096,4096)
  float* out = (float*)d_out;                  // (1,4096,4096) f32

  char* p = (char*)d_ws;
  auto alloc = [&](size_t bytes) {
    char* r = p;
    p += (bytes + 255) & ~(size_t)255;
    return r;
  };
  u16*   xh   = (u16*)alloc((size_t)S * DIM * 2);        // 32 MB x hi (rne bf16)
  u16*   xl   = (u16*)alloc((size_t)S * DIM * 2);        // 32 MB x lo residual
  u16*   wqb  = (u16*)alloc((size_t)NQKV * DIM * 2);     // 48 MB wqkv bf16
  u16*   wkl  = (u16*)alloc((size_t)HL * D * DIM * 2);   //  8 MB K-head lo residual
  u16*   wob  = (u16*)alloc((size_t)DIM * DIM * 2);      // 32 MB wo bf16
  u16*   qkvb = (u16*)alloc((size_t)S * NQKV * 2);       // 48 MB bf16 qkv
  float* kf32 = (float*)alloc((size_t)S * HL * D * 4);   // 16 MB precise k
  u16*   qb   = (u16*)alloc((size_t)H * S * D * 2);      // 32 MB (H,S,D)
  u16*   kb   = (u16*)alloc((size_t)HL * S * D * 2);     //  8 MB (HL,S,D)
  u16*   vbt  = (u16*)alloc((size_t)HL * D * S * 2);     //  8 MB (HL,D,S)
  float* krep = (float*)alloc((size_t)TB * HL * D * 4);  //  2 MB
  float* XC   = (float*)alloc((size_t)64 * DIM * 4);     //  1 MB
  float* XD   = (float*)alloc((size_t)64 * DIM * 4);     //  1 MB
  float* M1   = (float*)alloc((size_t)H * D * 4);
  float* M2   = (float*)alloc((size_t)H * D * 4);
  int*   bidx = (int*)alloc((size_t)H * KL * 4);
  u16*   attno = (u16*)alloc((size_t)S * DIM * 2);       // 32 MB

  hipMemsetAsync(XC, 0, (size_t)64 * DIM * 4, stream);
  hipMemsetAsync(XD, 0, (size_t)64 * DIM * 4, stream);

  // ---- conversion passes (memory-bound) ----
  split_f32_kernel<<<(S * DIM) / 2048, 256, 0, stream>>>(x, xh, xl);
  conv_wqkv_kernel<<<(NQKV * DIM) / 2048, 256, 0, stream>>>(wqkv, wqb, wkl);
  cast_bf16_kernel<<<(DIM * DIM) / 2048, 256, 0, stream>>>(wo, wob);

  // ---- bf16 qkv: Q cols + V cols only (K cols of qkvb are never read) ----
  gemm_bf16<true><<<dim3((H * D) / 128, S / 128), 256, 0, stream>>>(
      xh, wqb, qkvb, S, H * D, DIM, DIM, DIM, NQKV);
  gemm_bf16<true><<<dim3((HL * D) / 128, S / 128), 256, 0, stream>>>(
      xh, wqb + (size_t)(H + HL) * D * DIM, qkvb + (H + HL) * D,
      S, HL * D, DIM, DIM, DIM, NQKV);

  // ---- precise K heads: fused (Al*Bh + Ah*Bl + Ah*Bh), single pass ----
  const u16* wkh = wqb + (size_t)H * D * DIM;  // K-head hi rows 4096..5119
  gemm_k3<<<dim3((HL * D) / 64, S / 128), 256, 0, stream>>>(
      xh, xl, wkh, wkl, kf32, S, HL * D, DIM);

  // ---- exact q_mean via rope linearity (f32 inputs, unchanged) ----
  xcd_kernel<<<dim3(32, 2, 32), 128, 0, stream>>>(x, freqs, XC, XD);
  mrow_kernel<<<1024, 256, 0, stream>>>(wqkv, XC, XD, M1, M2);
  rope_q_kernel<<<dim3(S / 64, H), 256, 0, stream>>>(qkvb, freqs, qb);
  rope_kv_kernel<<<dim3(TB, HL), 128, 0, stream>>>(kf32, qkvb, freqs, kb, vbt, krep);
  topk_kernel<<<H, 512, 0, stream>>>(M1, M2, krep, bidx);
  attn_mfma<<<dim3(S / 64, H), 256, 0, stream>>>(qb, kb, vbt, bidx, attno);
  gemm_bf16<false><<<dim3(DIM / 128, S / 128), 256, 0, stream>>>(
      attno, wob, out, S, DIM, DIM, DIM, DIM, DIM);
}

// Round 3
// 1307.573 us; speedup vs baseline: 1.3251x; 1.1206x over previous
//
#include <hip/hip_runtime.h>
#include <hip/hip_bf16.h>

typedef unsigned short u16;
typedef unsigned int   u32;

using bf16x8 = __attribute__((ext_vector_type(8))) short;
using f32x4  = __attribute__((ext_vector_type(4))) float;

constexpr int S = 4096, DIM = 4096, H = 32, HL = 8, D = 128;
constexpr int NQKV = (H + 2 * HL) * D;   // 6144
constexpr int QVW = (H + HL) * D;        // 5120: packed [Q | V] width
constexpr int TB = S / 8;                // 512 blocks of 8 tokens
constexpr int KL = 108;                  // 4 sink + 4 window + 100 heavy
constexpr float NEGF = -1e30f;
constexpr float SCALE = 0.08838834764831845f;  // 1/sqrt(128)

__device__ inline float bflo(u32 u) { return __builtin_bit_cast(float, u << 16); }
__device__ inline float bfhi(u32 u) { return __builtin_bit_cast(float, u & 0xFFFF0000u); }
__device__ inline u16 rne16(float f) {
  u32 b = __builtin_bit_cast(u32, f);
  return (u16)((b + 0x7FFFu + ((b >> 16) & 1u)) >> 16);
}
__device__ inline float bf2f(u16 h) { return __builtin_bit_cast(float, (u32)h << 16); }
__device__ inline u32 pk2(u16 a, u16 b) { return (u32)a | ((u32)b << 16); }

// async global->LDS, 16B per lane. LDS dest = wave-uniform base + lane*16.
__device__ __forceinline__ void gload16(const u16* g, u16* l) {
  __builtin_amdgcn_global_load_lds(
      (__attribute__((address_space(1))) void*)g,
      (__attribute__((address_space(3))) void*)l, 16, 0, 0);
}

// bijective XCD-aware swizzle of the flat workgroup id (nwg % 8 == 0).
__device__ inline void xcd_swz(int nx, int& bx, int& by) {
  const int flat = blockIdx.y * nx + blockIdx.x;
  const int nwg = nx * gridDim.y;
  const int cpx = nwg >> 3;
  const int s = (flat & 7) * cpx + (flat >> 3);
  bx = s % nx;
  by = s / nx;
}

// ================= conversion passes (memory-bound, one-shot) ===============
__global__ __launch_bounds__(256) void split_f32_kernel(
    const float* __restrict__ src, u16* __restrict__ hi, u16* __restrict__ lo) {
  const size_t i = ((size_t)blockIdx.x * 256 + threadIdx.x) * 8;
  float4 v0 = *(const float4*)(src + i);
  float4 v1 = *(const float4*)(src + i + 4);
  float f[8] = {v0.x, v0.y, v0.z, v0.w, v1.x, v1.y, v1.z, v1.w};
  u16 h[8], l[8];
#pragma unroll
  for (int j = 0; j < 8; ++j) {
    h[j] = rne16(f[j]);
    l[j] = rne16(f[j] - bf2f(h[j]));
  }
  uint4 ph, pl;
  ph.x = pk2(h[0], h[1]); ph.y = pk2(h[2], h[3]);
  ph.z = pk2(h[4], h[5]); ph.w = pk2(h[6], h[7]);
  pl.x = pk2(l[0], l[1]); pl.y = pk2(l[2], l[3]);
  pl.z = pk2(l[4], l[5]); pl.w = pk2(l[6], l[7]);
  *(uint4*)(hi + i) = ph;
  *(uint4*)(lo + i) = pl;
}

// wqkv f32 -> packed bf16 [Q rows | V rows] + K-head hi/lo separate buffers.
__global__ __launch_bounds__(256) void conv_wqkv_kernel(
    const float* __restrict__ src, u16* __restrict__ wqv,
    u16* __restrict__ wkh, u16* __restrict__ wkl) {
  const size_t i = ((size_t)blockIdx.x * 256 + threadIdx.x) * 8;
  float4 v0 = *(const float4*)(src + i);
  float4 v1 = *(const float4*)(src + i + 4);
  float f[8] = {v0.x, v0.y, v0.z, v0.w, v1.x, v1.y, v1.z, v1.w};
  u16 h[8];
#pragma unroll
  for (int j = 0; j < 8; ++j) h[j] = rne16(f[j]);
  uint4 ph;
  ph.x = pk2(h[0], h[1]); ph.y = pk2(h[2], h[3]);
  ph.z = pk2(h[4], h[5]); ph.w = pk2(h[6], h[7]);
  const int row = (int)(i >> 12);
  if (row < H * D) {                       // Q rows -> wqv[0..4095]
    *(uint4*)(wqv + i) = ph;
  } else if (row < (H + HL) * D) {         // K rows -> wkh/wkl
    const size_t off = i - (size_t)(H * D) * DIM;
    u16 l[8];
#pragma unroll
    for (int j = 0; j < 8; ++j) l[j] = rne16(f[j] - bf2f(h[j]));
    uint4 pl;
    pl.x = pk2(l[0], l[1]); pl.y = pk2(l[2], l[3]);
    pl.z = pk2(l[4], l[5]); pl.w = pk2(l[6], l[7]);
    *(uint4*)(wkh + off) = ph;
    *(uint4*)(wkl + off) = pl;
  } else {                                 // V rows -> wqv[4096..5119]
    *(uint4*)(wqv + (i - (size_t)(HL * D) * DIM)) = ph;
  }
}

__global__ __launch_bounds__(256) void cast_bf16_kernel(
    const float* __restrict__ src, u16* __restrict__ dst) {
  const size_t i = ((size_t)blockIdx.x * 256 + threadIdx.x) * 8;
  float4 v0 = *(const float4*)(src + i);
  float4 v1 = *(const float4*)(src + i + 4);
  uint4 ph;
  ph.x = pk2(rne16(v0.x), rne16(v0.y));
  ph.y = pk2(rne16(v0.z), rne16(v0.w));
  ph.z = pk2(rne16(v1.x), rne16(v1.y));
  ph.w = pk2(rne16(v1.z), rne16(v1.w));
  *(uint4*)(dst + i) = ph;
}

// ============ bf16 GEMM: C[M,N] = A[M,K] * B[N,K]^T =========================
// 128x128 tile, BK=32, 4 waves, global_load_lds staging, linear LDS,
// 2-phase double-buffered pipeline: stage(next) BEFORE compute(cur), one
// __syncthreads (vmcnt(0)+barrier) per K-step at loop bottom. [T3 minimum]
template <bool OBF16>
__global__ __launch_bounds__(256) void gemm_bf16(
    const u16* __restrict__ A, const u16* __restrict__ B,
    void* __restrict__ Cp, int M, int N, int K, int lda, int ldb, int ldc) {
  __shared__ u16 As[2][128 * 32];
  __shared__ u16 Bs[2][128 * 32];
  const int tid = threadIdx.x;
  const int lane = tid & 63;
  const int w = tid >> 6;
  const int wm = w >> 1, wn = w & 1;
  int bx, by;
  xcd_swz(gridDim.x, bx, by);
  const int m0 = by * 128, n0 = bx * 128;
  const int l15 = lane & 15, g = lane >> 4;
  const int srow = tid >> 2;          // 0..63
  const int scol = (tid & 3) * 8;     // u16 units: 0,8,16,24

  const u16* ga = A + (size_t)(m0 + srow) * lda + scol;
  const u16* gb = B + (size_t)(n0 + srow) * ldb + scol;
  const size_t a64 = (size_t)64 * lda;
  const size_t b64 = (size_t)64 * ldb;

  auto stage = [&](int buf, int k0) {
    u16* lA = As[buf] + w * 512;      // 1024 B per wave
    u16* lB = Bs[buf] + w * 512;
    gload16(ga + k0, lA);             // A rows 0..63
    gload16(ga + k0 + a64, lA + 2048);// A rows 64..127
    gload16(gb + k0, lB);             // B rows 0..63
    gload16(gb + k0 + b64, lB + 2048);// B rows 64..127
  };

  f32x4 acc[4][4];
#pragma unroll
  for (int i = 0; i < 4; ++i)
#pragma unroll
    for (int j = 0; j < 4; ++j) acc[i][j] = {0.f, 0.f, 0.f, 0.f};

  stage(0, 0);
  __syncthreads();
  const int niter = K / 32;
  for (int it = 0; it < niter; ++it) {
    const int cur = it & 1;
    if (it + 1 < niter) stage(cur ^ 1, (it + 1) * 32);  // prefetch in flight
    bf16x8 af[4], bfr[4];
#pragma unroll
    for (int i = 0; i < 4; ++i)
      af[i] = *(const bf16x8*)(As[cur] + (wm * 64 + i * 16 + l15) * 32 + g * 8);
#pragma unroll
    for (int j = 0; j < 4; ++j)
      bfr[j] = *(const bf16x8*)(Bs[cur] + (wn * 64 + j * 16 + l15) * 32 + g * 8);
#pragma unroll
    for (int i = 0; i < 4; ++i)
#pragma unroll
      for (int j = 0; j < 4; ++j)
        acc[i][j] = __builtin_amdgcn_mfma_f32_16x16x32_bf16(af[i], bfr[j], acc[i][j], 0, 0, 0);
    __syncthreads();  // drains prefetch (hidden behind MFMA) + barrier
  }
  // C/D layout: col = lane&15, row = (lane>>4)*4 + reg   [verified m89/m91]
#pragma unroll
  for (int i = 0; i < 4; ++i)
#pragma unroll
    for (int j = 0; j < 4; ++j)
#pragma unroll
      for (int rg = 0; rg < 4; ++rg) {
        const int row = m0 + wm * 64 + i * 16 + g * 4 + rg;
        const int col = n0 + wn * 64 + j * 16 + l15;
        if constexpr (OBF16)
          ((u16*)Cp)[(size_t)row * ldc + col] = rne16(acc[i][j][rg]);
        else
          ((float*)Cp)[(size_t)row * ldc + col] = acc[i][j][rg];
      }
}

// ============ fused 3-term split GEMM: C = Al*Bh^T + Ah*Bl^T + Ah*Bh^T ======
// Near-f32 precision for the K-head path. Tile 128(M)x64(N), BK=32, 4 waves,
// same 2-phase double-buffered pipeline.
__global__ __launch_bounds__(256) void gemm_k3(
    const u16* __restrict__ Ahg, const u16* __restrict__ Alg,
    const u16* __restrict__ Bhg, const u16* __restrict__ Blg,
    float* __restrict__ C, int M, int N, int K) {
  __shared__ u16 Ah[2][128 * 32];
  __shared__ u16 Al[2][128 * 32];
  __shared__ u16 Bh[2][64 * 32];
  __shared__ u16 Bl[2][64 * 32];
  const int tid = threadIdx.x;
  const int lane = tid & 63;
  const int w = tid >> 6;
  const int wm = w >> 1, wn = w & 1;   // wave tile: 64(M) x 32(N)
  int bx, by;
  xcd_swz(gridDim.x, bx, by);
  const int m0 = by * 128, n0 = bx * 64;
  const int l15 = lane & 15, g = lane >> 4;
  const int srow = tid >> 2;           // 0..63
  const int scol = (tid & 3) * 8;

  const u16* gah = Ahg + (size_t)(m0 + srow) * K + scol;
  const u16* gal = Alg + (size_t)(m0 + srow) * K + scol;
  const u16* gbh = Bhg + (size_t)(n0 + srow) * K + scol;
  const u16* gbl = Blg + (size_t)(n0 + srow) * K + scol;
  const size_t a64 = (size_t)64 * K;

  auto stage = [&](int buf, int k0) {
    gload16(gah + k0, Ah[buf] + w * 512);
    gload16(gah + k0 + a64, Ah[buf] + w * 512 + 2048);
    gload16(gal + k0, Al[buf] + w * 512);
    gload16(gal + k0 + a64, Al[buf] + w * 512 + 2048);
    gload16(gbh + k0, Bh[buf] + w * 512);
    gload16(gbl + k0, Bl[buf] + w * 512);
  };

  f32x4 acc[4][2];
#pragma unroll
  for (int i = 0; i < 4; ++i)
#pragma unroll
    for (int j = 0; j < 2; ++j) acc[i][j] = {0.f, 0.f, 0.f, 0.f};

  stage(0, 0);
  __syncthreads();
  const int niter = K / 32;
  for (int it = 0; it < niter; ++it) {
    const int cur = it & 1;
    if (it + 1 < niter) stage(cur ^ 1, (it + 1) * 32);
    bf16x8 fah[4], fal[4], fbh[2], fbl[2];
#pragma unroll
    for (int i = 0; i < 4; ++i) {
      fah[i] = *(const bf16x8*)(Ah[cur] + (wm * 64 + i * 16 + l15) * 32 + g * 8);
      fal[i] = *(const bf16x8*)(Al[cur] + (wm * 64 + i * 16 + l15) * 32 + g * 8);
    }
#pragma unroll
    for (int j = 0; j < 2; ++j) {
      fbh[j] = *(const bf16x8*)(Bh[cur] + (wn * 32 + j * 16 + l15) * 32 + g * 8);
      fbl[j] = *(const bf16x8*)(Bl[cur] + (wn * 32 + j * 16 + l15) * 32 + g * 8);
    }
#pragma unroll
    for (int i = 0; i < 4; ++i)
#pragma unroll
      for (int j = 0; j < 2; ++j) {
        acc[i][j] = __builtin_amdgcn_mfma_f32_16x16x32_bf16(fal[i], fbh[j], acc[i][j], 0, 0, 0);
        acc[i][j] = __builtin_amdgcn_mfma_f32_16x16x32_bf16(fah[i], fbl[j], acc[i][j], 0, 0, 0);
        acc[i][j] = __builtin_amdgcn_mfma_f32_16x16x32_bf16(fah[i], fbh[j], acc[i][j], 0, 0, 0);
      }
    __syncthreads();
  }
#pragma unroll
  for (int i = 0; i < 4; ++i)
#pragma unroll
    for (int j = 0; j < 2; ++j)
#pragma unroll
      for (int rg = 0; rg < 4; ++rg) {
        const int row = m0 + wm * 64 + i * 16 + g * 4 + rg;
        const int col = n0 + wn * 32 + j * 16 + l15;
        C[(size_t)row * N + col] = acc[i][j][rg];
      }
}

// ---------------- XC/XD: weighted token-sums of x (exact q_mean path) -------
__global__ __launch_bounds__(128) void xcd_kernel(
    const float* __restrict__ x, const float* __restrict__ freqs,
    float* __restrict__ XC, float* __restrict__ XD) {
  const int d = blockIdx.x * 128 + threadIdx.x;
  const int i0 = blockIdx.y * 32;
  const int s0 = blockIdx.z * 128;
  float accC[32], accD[32];
#pragma unroll
  for (int ii = 0; ii < 32; ++ii) { accC[ii] = 0.f; accD[ii] = 0.f; }
  for (int s = s0; s < s0 + 128; ++s) {
    const float xv = x[(size_t)s * DIM + d];
    const float* fr = freqs + (size_t)s * 128 + i0 * 2;  // block-uniform -> s_loads
#pragma unroll
    for (int ii = 0; ii < 32; ++ii) {
      accC[ii] += fr[2 * ii] * xv;
      accD[ii] += fr[2 * ii + 1] * xv;
    }
  }
#pragma unroll
  for (int ii = 0; ii < 32; ++ii) {
    atomicAdd(&XC[(size_t)(i0 + ii) * DIM + d], accC[ii]);
    atomicAdd(&XD[(size_t)(i0 + ii) * DIM + d], accD[ii]);
  }
}

// ---------------- M1/M2: per-q-row dots with XC/XD --------------------------
__global__ __launch_bounds__(256) void mrow_kernel(
    const float* __restrict__ wq, const float* __restrict__ XC,
    const float* __restrict__ XD, float* __restrict__ M1, float* __restrict__ M2) {
  const int r = blockIdx.x * 4 + (threadIdx.x >> 6);
  const int lane = threadIdx.x & 63;
  const int i = (r & 127) >> 1;
  const float* wr = wq + (size_t)r * DIM;
  const float* xc = XC + (size_t)i * DIM;
  const float* xd = XD + (size_t)i * DIM;
  float s1 = 0.f, s2 = 0.f;
  for (int k = lane; k < DIM; k += 64) {
    float wv = wr[k];
    s1 += wv * xc[k];
    s2 += wv * xd[k];
  }
#pragma unroll
  for (int off = 1; off < 64; off <<= 1) {
    s1 += __shfl_xor(s1, off, 64);
    s2 += __shfl_xor(s2, off, 64);
  }
  if (lane == 0) { M1[r] = s1; M2[r] = s2; }
}

// ---------------- RoPE on Q (bf16 in, bf16 out) -----------------------------
__global__ __launch_bounds__(256) void rope_q_kernel(
    const u16* __restrict__ qvb, const float* __restrict__ freqs,
    u16* __restrict__ qb) {
  const int h = blockIdx.y;
  const int s0 = blockIdx.x * 64;
  const int tid = threadIdx.x;
  const int d = tid & 127, half = tid >> 7;
  for (int pp = half; pp < 64; pp += 2) {
    const int s = s0 + pp;
    u32 pr = *(const u32*)(qvb + (size_t)s * QVW + h * D + (d & ~1));
    float a = bflo(pr), b = bfhi(pr);
    float2 fc = *(const float2*)(freqs + (size_t)s * 128 + (d & ~1));
    float o = (d & 1) ? (b * fc.x + a * fc.y) : (a * fc.x - b * fc.y);
    qb[((size_t)h * S + s) * D + d] = rne16(o);
  }
}

// ---------------- RoPE on precise K + block means; V cast + transpose -------
__global__ __launch_bounds__(128) void rope_kv_kernel(
    const float* __restrict__ kf, const u16* __restrict__ qvb,
    const float* __restrict__ freqs,
    u16* __restrict__ kb, u16* __restrict__ vbt, float* __restrict__ krep) {
  const int hl = blockIdx.y;
  const int t = blockIdx.x;  // token block 0..511
  const int d = threadIdx.x;
  float sum = 0.f;
  u16 vv[8];
#pragma unroll
  for (int pp = 0; pp < 8; ++pp) {
    const int s = t * 8 + pp;
    float2 kp = *(const float2*)(kf + (size_t)s * 1024 + hl * D + (d & ~1));
    float2 fc = *(const float2*)(freqs + (size_t)s * 128 + (d & ~1));
    float o = (d & 1) ? (kp.y * fc.x + kp.x * fc.y) : (kp.x * fc.x - kp.y * fc.y);
    kb[((size_t)hl * S + s) * D + d] = rne16(o);
    sum += o;
    vv[pp] = qvb[(size_t)s * QVW + H * D + hl * D + d];  // V at packed col 4096+
  }
  krep[((size_t)t * HL + hl) * D + d] = sum * 0.125f;
  uint4 pk;
  pk.x = pk2(vv[0], vv[1]);
  pk.y = pk2(vv[2], vv[3]);
  pk.z = pk2(vv[4], vv[5]);
  pk.w = pk2(vv[6], vv[7]);
  *(uint4*)(vbt + ((size_t)hl * D + d) * S + t * 8) = pk;
}

// ---------------- scores + top-100 selection per head -----------------------
__global__ __launch_bounds__(512) void topk_kernel(
    const float* __restrict__ M1, const float* __restrict__ M2,
    const float* __restrict__ krep, int* __restrict__ bidx) {
  const int h = blockIdx.x;
  const int t = threadIdx.x;  // block id 0..511
  __shared__ float qm[128];
  if (t < 128) {
    int r = h * 128 + t;
    float v = (t & 1) ? (M1[r] + M2[r - 1]) : (M1[r] - M2[r + 1]);
    qm[t] = v * (1.f / 4096.f);
  }
  __syncthreads();
  const float* kr = krep + ((size_t)t * HL + (h >> 2)) * 128;
  float s = 0.f;
#pragma unroll 8
  for (int d = 0; d < 128; ++d) s += qm[d] * kr[d];
  s *= SCALE;
  if (t < 4 || t >= 508) s = NEGF;  // sink + window masked out of top-k
  if (t < 4) {
    bidx[h * KL + t] = t;            // sink blocks 0..3
    bidx[h * KL + 4 + t] = 508 + t;  // window blocks 508..511
  }
  __shared__ float wv[8];
  __shared__ int wi[8];
  __shared__ int bestsh;
  for (int iter = 0; iter < 100; ++iter) {
    float v = s;
    int idx = t;
#pragma unroll
    for (int off = 1; off < 64; off <<= 1) {
      float ov = __shfl_xor(v, off, 64);
      int oi = __shfl_xor(idx, off, 64);
      if (ov > v || (ov == v && oi < idx)) { v = ov; idx = oi; }
    }
    if ((t & 63) == 0) { wv[t >> 6] = v; wi[t >> 6] = idx; }
    __syncthreads();
    if (t == 0) {
      float bv = wv[0];
      int bi = wi[0];
#pragma unroll
      for (int u = 1; u < 8; ++u)
        if (wv[u] > bv || (wv[u] == bv && wi[u] < bi)) { bv = wv[u]; bi = wi[u]; }
      bestsh = bi;
      bidx[h * KL + 8 + iter] = bi;
    }
    __syncthreads();
    if (t == bestsh) s = NEGF;
  }
}

// ---------------- MFMA flash attention over selected blocks -----------------
__global__ __launch_bounds__(256) void attn_mfma(
    const u16* __restrict__ qb, const u16* __restrict__ kb,
    const u16* __restrict__ vbt, const int* __restrict__ bidx,
    u16* __restrict__ attno) {
  __shared__ u16 Ks[32][136];   // 32 toks x 128 d (+8 pad)
  __shared__ u16 Vt[128][40];   // 128 d x 32 toks (+8 pad)
  __shared__ u16 Ps[4][16][40]; // per wave: 16 rows x 32 toks (+8 pad)
  const int h = blockIdx.y, hl = h >> 2;
  const int q0 = blockIdx.x * 64;
  const int tid = threadIdx.x;
  const int w = tid >> 6, lane = tid & 63;
  const int l15 = lane & 15, g = lane >> 4;

  bf16x8 qf[4];
  {
    const u16* qp = qb + ((size_t)h * S + q0 + w * 16 + l15) * D + g * 8;
#pragma unroll
    for (int c = 0; c < 4; ++c) qf[c] = *(const bf16x8*)(qp + c * 32);
  }
  f32x4 o[8];
#pragma unroll
  for (int c = 0; c < 8; ++c) o[c] = {0.f, 0.f, 0.f, 0.f};
  float mrow[4], lrow[4];
#pragma unroll
  for (int r = 0; r < 4; ++r) { mrow[r] = NEGF; lrow[r] = 0.f; }

  for (int step = 0; step < KL / 4; ++step) {
    const int b0 = bidx[h * KL + step * 4 + 0];
    const int b1 = bidx[h * KL + step * 4 + 1];
    const int b2 = bidx[h * KL + step * 4 + 2];
    const int b3 = bidx[h * KL + step * 4 + 3];
    {  // stage K: tok = tid>>3, seg = tid&7 (32B contiguous per thread)
      const int tok = tid >> 3, seg = tid & 7;
      const int blk = (tok < 8) ? b0 : (tok < 16) ? b1 : (tok < 24) ? b2 : b3;
      const u16* src = kb + ((size_t)hl * S + blk * 8 + (tok & 7)) * D + seg * 16;
      *(uint4*)&Ks[tok][seg * 16] = *(const uint4*)src;
      *(uint4*)&Ks[tok][seg * 16 + 8] = *(const uint4*)(src + 8);
    }
    {  // stage V^T: d = tid>>1, half = tid&1 (two 8-token runs)
      const int d = tid >> 1, hf = tid & 1;
      const int ba = hf ? b2 : b0, bb = hf ? b3 : b1;
      const u16* src = vbt + ((size_t)hl * D + d) * S;
      *(uint4*)&Vt[d][hf * 16] = *(const uint4*)(src + ba * 8);
      *(uint4*)&Vt[d][hf * 16 + 8] = *(const uint4*)(src + bb * 8);
    }
    __syncthreads();
    // QK^T: two 16x16 tiles (toks 0..15, 16..31)
    f32x4 sA = {0.f, 0.f, 0.f, 0.f}, sB = {0.f, 0.f, 0.f, 0.f};
#pragma unroll
    for (int c = 0; c < 4; ++c) {
      bf16x8 k0 = *(const bf16x8*)&Ks[l15][c * 32 + g * 8];
      bf16x8 k1 = *(const bf16x8*)&Ks[16 + l15][c * 32 + g * 8];
      sA = __builtin_amdgcn_mfma_f32_16x16x32_bf16(qf[c], k0, sA, 0, 0, 0);
      sB = __builtin_amdgcn_mfma_f32_16x16x32_bf16(qf[c], k1, sB, 0, 0, 0);
    }
    const int tgA = ((l15 < 8) ? b0 : b1) * 8 + (l15 & 7);
    const int tgB = ((l15 < 8) ? b2 : b3) * 8 + (l15 & 7);
    float pA[4], pB[4], alpha[4];
#pragma unroll
    for (int r = 0; r < 4; ++r) {
      const int sq = q0 + w * 16 + g * 4 + r;
      pA[r] = (tgA <= sq) ? sA[r] * SCALE : NEGF;
      pB[r] = (tgB <= sq) ? sB[r] * SCALE : NEGF;
      float mx = fmaxf(pA[r], pB[r]);
      mx = fmaxf(mx, __shfl_xor(mx, 1, 64));
      mx = fmaxf(mx, __shfl_xor(mx, 2, 64));
      mx = fmaxf(mx, __shfl_xor(mx, 4, 64));
      mx = fmaxf(mx, __shfl_xor(mx, 8, 64));
      const float mnew = fmaxf(mrow[r], mx);
      alpha[r] = __expf(mrow[r] - mnew);
      mrow[r] = mnew;
      pA[r] = __expf(pA[r] - mnew);
      pB[r] = __expf(pB[r] - mnew);
      float rs = pA[r] + pB[r];
      rs += __shfl_xor(rs, 1, 64);
      rs += __shfl_xor(rs, 2, 64);
      rs += __shfl_xor(rs, 4, 64);
      rs += __shfl_xor(rs, 8, 64);
      lrow[r] = lrow[r] * alpha[r] + rs;
    }
#pragma unroll
    for (int c = 0; c < 8; ++c) {
      o[c][0] *= alpha[0]; o[c][1] *= alpha[1];
      o[c][2] *= alpha[2]; o[c][3] *= alpha[3];
    }
    // P: C-layout -> LDS -> A-layout (within-wave, in-order LDS)
#pragma unroll
    for (int r = 0; r < 4; ++r) {
      Ps[w][g * 4 + r][l15] = rne16(pA[r]);
      Ps[w][g * 4 + r][16 + l15] = rne16(pB[r]);
    }
    bf16x8 pf = *(const bf16x8*)&Ps[w][l15][g * 8];
#pragma unroll
    for (int c = 0; c < 8; ++c) {
      bf16x8 vf = *(const bf16x8*)&Vt[c * 16 + l15][g * 8];
      o[c] = __builtin_amdgcn_mfma_f32_16x16x32_bf16(pf, vf, o[c], 0, 0, 0);
    }
    __syncthreads();
  }
  float inv[4];
#pragma unroll
  for (int r = 0; r < 4; ++r) inv[r] = 1.f / lrow[r];
#pragma unroll
  for (int c = 0; c < 8; ++c)
#pragma unroll
    for (int r = 0; r < 4; ++r)
      attno[(size_t)(q0 + w * 16 + g * 4 + r) * DIM + h * D + c * 16 + l15] =
          rne16(o[c][r] * inv[r]);
}

extern "C" void kernel_launch(void* const* d_in, const int* in_sizes, int n_in,
                              void* d_out, int out_size, void* d_ws, size_t ws_size,
                              hipStream_t stream) {
  const float* x     = (const float*)d_in[0];  // (1,4096,4096)
  const float* freqs = (const float*)d_in[1];  // (4096,64,2)
  const float* wqkv  = (const float*)d_in[2];  // (6144,4096)
  const float* wo    = (const float*)d_in[3];  // (4096,4096)
  float* out = (float*)d_out;                  // (1,4096,4096) f32

  char* p = (char*)d_ws;
  auto alloc = [&](size_t bytes) {
    char* r = p;
    p += (bytes + 255) & ~(size_t)255;
    return r;
  };
  u16*   xh   = (u16*)alloc((size_t)S * DIM * 2);        // 32 MB x hi (rne bf16)
  u16*   xl   = (u16*)alloc((size_t)S * DIM * 2);        // 32 MB x lo residual
  u16*   wqv  = (u16*)alloc((size_t)QVW * DIM * 2);      // 40 MB packed [Q|V] bf16
  u16*   wkh  = (u16*)alloc((size_t)HL * D * DIM * 2);   //  8 MB K-head hi
  u16*   wkl  = (u16*)alloc((size_t)HL * D * DIM * 2);   //  8 MB K-head lo
  u16*   wob  = (u16*)alloc((size_t)DIM * DIM * 2);      // 32 MB wo bf16
  u16*   qvb  = (u16*)alloc((size_t)S * QVW * 2);        // 40 MB bf16 [Q|V]
  float* kf32 = (float*)alloc((size_t)S * HL * D * 4);   // 16 MB precise k
  u16*   qb   = (u16*)alloc((size_t)H * S * D * 2);      // 32 MB (H,S,D)
  u16*   kb   = (u16*)alloc((size_t)HL * S * D * 2);     //  8 MB (HL,S,D)
  u16*   vbt  = (u16*)alloc((size_t)HL * D * S * 2);     //  8 MB (HL,D,S)
  float* krep = (float*)alloc((size_t)TB * HL * D * 4);  //  2 MB
  float* XC   = (float*)alloc((size_t)64 * DIM * 4);     //  1 MB
  float* XD   = (float*)alloc((size_t)64 * DIM * 4);     //  1 MB
  float* M1   = (float*)alloc((size_t)H * D * 4);
  float* M2   = (float*)alloc((size_t)H * D * 4);
  int*   bidx = (int*)alloc((size_t)H * KL * 4);
  u16*   attno = (u16*)alloc((size_t)S * DIM * 2);       // 32 MB

  hipMemsetAsync(XC, 0, (size_t)64 * DIM * 4, stream);
  hipMemsetAsync(XD, 0, (size_t)64 * DIM * 4, stream);

  // ---- conversion passes (memory-bound) ----
  split_f32_kernel<<<(S * DIM) / 2048, 256, 0, stream>>>(x, xh, xl);
  conv_wqkv_kernel<<<(NQKV * DIM) / 2048, 256, 0, stream>>>(wqkv, wqv, wkh, wkl);
  cast_bf16_kernel<<<(DIM * DIM) / 2048, 256, 0, stream>>>(wo, wob);

  // ---- bf16 Q+V (one launch, packed N=5120) ----
  gemm_bf16<true><<<dim3(QVW / 128, S / 128), 256, 0, stream>>>(
      xh, wqv, qvb, S, QVW, DIM, DIM, DIM, QVW);

  // ---- precise K heads: fused (Al*Bh + Ah*Bl + Ah*Bh), single pass ----
  gemm_k3<<<dim3((HL * D) / 64, S / 128), 256, 0, stream>>>(
      xh, xl, wkh, wkl, kf32, S, HL * D, DIM);

  // ---- exact q_mean via rope linearity (f32 inputs, unchanged) ----
  xcd_kernel<<<dim3(32, 2, 32), 128, 0, stream>>>(x, freqs, XC, XD);
  mrow_kernel<<<1024, 256, 0, stream>>>(wqkv, XC, XD, M1, M2);
  rope_q_kernel<<<dim3(S / 64, H), 256, 0, stream>>>(qvb, freqs, qb);
  rope_kv_kernel<<<dim3(TB, HL), 128, 0, stream>>>(kf32, qvb, freqs, kb, vbt, krep);
  topk_kernel<<<H, 512, 0, stream>>>(M1, M2, krep, bidx);
  attn_mfma<<<dim3(S / 64, H), 256, 0, stream>>>(qb, kb, vbt, bidx, attno);
  gemm_bf16<false><<<dim3(DIM / 128, S / 128), 256, 0, stream>>>(
      attno, wob, out, S, DIM, DIM, DIM, DIM, DIM);
}

// Round 4
// 1267.434 us; speedup vs baseline: 1.3671x; 1.0317x over previous
//
#include <hip/hip_runtime.h>
#include <hip/hip_bf16.h>

typedef unsigned short u16;
typedef unsigned int   u32;

using bf16x8 = __attribute__((ext_vector_type(8))) short;
using f32x4  = __attribute__((ext_vector_type(4))) float;

constexpr int S = 4096, DIM = 4096, H = 32, HL = 8, D = 128;
constexpr int NQKV = (H + 2 * HL) * D;   // 6144
constexpr int QVW = (H + HL) * D;        // 5120: packed [Q | V] width
constexpr int TB = S / 8;                // 512 blocks of 8 tokens
constexpr int KL = 108;                  // 4 sink + 4 window + 100 heavy
constexpr float NEGF = -1e30f;
constexpr float SCALE = 0.08838834764831845f;  // 1/sqrt(128)

__device__ inline float bflo(u32 u) { return __builtin_bit_cast(float, u << 16); }
__device__ inline float bfhi(u32 u) { return __builtin_bit_cast(float, u & 0xFFFF0000u); }
__device__ inline u16 rne16(float f) {
  u32 b = __builtin_bit_cast(u32, f);
  return (u16)((b + 0x7FFFu + ((b >> 16) & 1u)) >> 16);
}
__device__ inline float bf2f(u16 h) { return __builtin_bit_cast(float, (u32)h << 16); }
__device__ inline u32 pk2(u16 a, u16 b) { return (u32)a | ((u32)b << 16); }

// async global->LDS, 16B per lane. LDS dest = wave-uniform base + lane*16.
__device__ __forceinline__ void gload16(const u16* g, u16* l) {
  __builtin_amdgcn_global_load_lds(
      (__attribute__((address_space(1))) void*)g,
      (__attribute__((address_space(3))) void*)l, 16, 0, 0);
}

// bijective XCD-aware swizzle of the flat workgroup id (nwg % 8 == 0).
__device__ inline void xcd_swz(int nx, int& bx, int& by) {
  const int flat = blockIdx.y * nx + blockIdx.x;
  const int nwg = nx * gridDim.y;
  const int cpx = nwg >> 3;
  const int s = (flat & 7) * cpx + (flat >> 3);
  bx = s % nx;
  by = s / nx;
}

// ================= conversion passes (memory-bound, one-shot) ===============
__global__ __launch_bounds__(256) void split_f32_kernel(
    const float* __restrict__ src, u16* __restrict__ hi, u16* __restrict__ lo) {
  const size_t i = ((size_t)blockIdx.x * 256 + threadIdx.x) * 8;
  float4 v0 = *(const float4*)(src + i);
  float4 v1 = *(const float4*)(src + i + 4);
  float f[8] = {v0.x, v0.y, v0.z, v0.w, v1.x, v1.y, v1.z, v1.w};
  u16 h[8], l[8];
#pragma unroll
  for (int j = 0; j < 8; ++j) {
    h[j] = rne16(f[j]);
    l[j] = rne16(f[j] - bf2f(h[j]));
  }
  uint4 ph, pl;
  ph.x = pk2(h[0], h[1]); ph.y = pk2(h[2], h[3]);
  ph.z = pk2(h[4], h[5]); ph.w = pk2(h[6], h[7]);
  pl.x = pk2(l[0], l[1]); pl.y = pk2(l[2], l[3]);
  pl.z = pk2(l[4], l[5]); pl.w = pk2(l[6], l[7]);
  *(uint4*)(hi + i) = ph;
  *(uint4*)(lo + i) = pl;
}

// wqkv f32 -> packed bf16 [Q rows | V rows] + K-head hi/lo separate buffers.
__global__ __launch_bounds__(256) void conv_wqkv_kernel(
    const float* __restrict__ src, u16* __restrict__ wqv,
    u16* __restrict__ wkh, u16* __restrict__ wkl) {
  const size_t i = ((size_t)blockIdx.x * 256 + threadIdx.x) * 8;
  float4 v0 = *(const float4*)(src + i);
  float4 v1 = *(const float4*)(src + i + 4);
  float f[8] = {v0.x, v0.y, v0.z, v0.w, v1.x, v1.y, v1.z, v1.w};
  u16 h[8];
#pragma unroll
  for (int j = 0; j < 8; ++j) h[j] = rne16(f[j]);
  uint4 ph;
  ph.x = pk2(h[0], h[1]); ph.y = pk2(h[2], h[3]);
  ph.z = pk2(h[4], h[5]); ph.w = pk2(h[6], h[7]);
  const int row = (int)(i >> 12);
  if (row < H * D) {                       // Q rows -> wqv[0..4095]
    *(uint4*)(wqv + i) = ph;
  } else if (row < (H + HL) * D) {         // K rows -> wkh/wkl
    const size_t off = i - (size_t)(H * D) * DIM;
    u16 l[8];
#pragma unroll
    for (int j = 0; j < 8; ++j) l[j] = rne16(f[j] - bf2f(h[j]));
    uint4 pl;
    pl.x = pk2(l[0], l[1]); pl.y = pk2(l[2], l[3]);
    pl.z = pk2(l[4], l[5]); pl.w = pk2(l[6], l[7]);
    *(uint4*)(wkh + off) = ph;
    *(uint4*)(wkl + off) = pl;
  } else {                                 // V rows -> wqv[4096..5119]
    *(uint4*)(wqv + (i - (size_t)(HL * D) * DIM)) = ph;
  }
}

__global__ __launch_bounds__(256) void cast_bf16_kernel(
    const float* __restrict__ src, u16* __restrict__ dst) {
  const size_t i = ((size_t)blockIdx.x * 256 + threadIdx.x) * 8;
  float4 v0 = *(const float4*)(src + i);
  float4 v1 = *(const float4*)(src + i + 4);
  uint4 ph;
  ph.x = pk2(rne16(v0.x), rne16(v0.y));
  ph.y = pk2(rne16(v0.z), rne16(v0.w));
  ph.z = pk2(rne16(v1.x), rne16(v1.y));
  ph.w = pk2(rne16(v1.z), rne16(v1.w));
  *(uint4*)(dst + i) = ph;
}

// ============ 8-phase 256x256 bf16 GEMM: C[M,N] = A[M,K] * B[N,K]^T =========
// BK=64, 8 waves (512 thr, 2Mx4N), per-wave C = 128x64, LDS 128 KiB
// (2 dbuf x (A 256x64 + B 256x64) bf16). T2 XOR-swizzle (16B-chunk j ^= row&7)
// applied via pre-swizzled GLOBAL source (linear global_load_lds dest, rule 21)
// + same XOR on ds_read. Counted vmcnt (T4): tile t+1's A issued at ph0 then
// vmcnt(4) -> all 8 loads of tile t complete, 4 newest stay in flight; B at ph1.
// Per phase: {ds_read subtile || stage} -> s_barrier -> setprio(1) MFMA
// setprio(0) -> s_barrier. Post-MFMA barrier makes stage-issue safe: a wave
// passing it implies ALL waves' ds_reads of the target buffer have completed.
template <bool OBF16>
__global__ __launch_bounds__(512, 2) void gemm256(
    const u16* __restrict__ A, const u16* __restrict__ B,
    void* __restrict__ Cp, int M, int N, int K, int lda, int ldb, int ldc) {
  __shared__ u16 lds[4 * 16384];  // [buf][A|B][256*64]
  const int tid = threadIdx.x;
  const int w = tid >> 6, lane = tid & 63;
  const int wm = w >> 2, wn = w & 3;          // 2 x 4 wave grid
  const int l15 = lane & 15, g = lane >> 4;
  int bx, by;
  xcd_swz(gridDim.x, bx, by);
  const int m0 = by * 256, n0 = bx * 256;

  // staging: round r covers chunk c = r*512+tid; row=c>>3, chunk-in-row j=c&7.
  // LDS dest linear; global source column pre-swizzled: j_src = j ^ (row&7).
  const u16* ga[4];
  const u16* gb[4];
#pragma unroll
  for (int r = 0; r < 4; ++r) {
    const int c = r * 512 + tid;
    const int row = c >> 3, j = c & 7;
    const int jsw = j ^ (row & 7);
    ga[r] = A + (size_t)(m0 + row) * lda + jsw * 8;
    gb[r] = B + (size_t)(n0 + row) * ldb + jsw * 8;
  }

  auto stageA = [&](int buf, int kt) {
    u16* base = lds + buf * 32768 + w * 512;
#pragma unroll
    for (int r = 0; r < 4; ++r) gload16(ga[r] + kt * 64, base + r * 4096);
  };
  auto stageB = [&](int buf, int kt) {
    u16* base = lds + buf * 32768 + 16384 + w * 512;
#pragma unroll
    for (int r = 0; r < 4; ++r) gload16(gb[r] + kt * 64, base + r * 4096);
  };

  bf16x8 afr[4][2], bfr[2][2];
  auto loadA = [&](int buf, int q) {
    const u16* Ab = lds + buf * 32768;
#pragma unroll
    for (int fr = 0; fr < 4; ++fr) {
      const int row = wm * 128 + q * 64 + fr * 16 + l15;
#pragma unroll
      for (int kh = 0; kh < 2; ++kh)
        afr[fr][kh] = *(const bf16x8*)(Ab + row * 64 + ((((kh << 2) | g)) ^ (l15 & 7)) * 8);
    }
  };
  auto loadB = [&](int buf, int r2) {
    const u16* Bb = lds + buf * 32768 + 16384;
#pragma unroll
    for (int fc = 0; fc < 2; ++fc) {
      const int row = wn * 64 + r2 * 32 + fc * 16 + l15;
#pragma unroll
      for (int kh = 0; kh < 2; ++kh)
        bfr[fc][kh] = *(const bf16x8*)(Bb + row * 64 + ((((kh << 2) | g)) ^ (l15 & 7)) * 8);
    }
  };

  f32x4 acc[8][4];
#pragma unroll
  for (int i = 0; i < 8; ++i)
#pragma unroll
    for (int j = 0; j < 4; ++j) acc[i][j] = {0.f, 0.f, 0.f, 0.f};

  auto mma = [&](int q, int r2) {
    __builtin_amdgcn_s_setprio(1);
#pragma unroll
    for (int fr = 0; fr < 4; ++fr)
#pragma unroll
      for (int fc = 0; fc < 2; ++fc)
#pragma unroll
        for (int kh = 0; kh < 2; ++kh)
          acc[q * 4 + fr][r2 * 2 + fc] = __builtin_amdgcn_mfma_f32_16x16x32_bf16(
              afr[fr][kh], bfr[fc][kh], acc[q * 4 + fr][r2 * 2 + fc], 0, 0, 0);
    __builtin_amdgcn_s_setprio(0);
  };

  stageA(0, 0);
  stageB(0, 0);
  const int NT = K / 64;
  for (int t = 0; t < NT; ++t) {
    const int cur = t & 1, nxt = cur ^ 1;
    // ---- phase 0: stage A(t+1); counted vmcnt; Q(0,0) ----
    if (t + 1 < NT) {
      stageA(nxt, t + 1);
      asm volatile("s_waitcnt vmcnt(4)" ::: "memory");
    } else {
      asm volatile("s_waitcnt vmcnt(0)" ::: "memory");
    }
    __builtin_amdgcn_sched_barrier(0);
    __builtin_amdgcn_s_barrier();
    loadA(cur, 0);
    loadB(cur, 0);
    mma(0, 0);
    __builtin_amdgcn_s_barrier();
    // ---- phase 1: stage B(t+1); Q(1,0) ----
    loadA(cur, 1);
    if (t + 1 < NT) stageB(nxt, t + 1);
    __builtin_amdgcn_s_barrier();
    mma(1, 0);
    __builtin_amdgcn_s_barrier();
    // ---- phase 2: Q(0,1) ----
    loadA(cur, 0);
    loadB(cur, 1);
    __builtin_amdgcn_s_barrier();
    mma(0, 1);
    __builtin_amdgcn_s_barrier();
    // ---- phase 3: Q(1,1) ----
    loadA(cur, 1);
    __builtin_amdgcn_s_barrier();
    mma(1, 1);
    __builtin_amdgcn_s_barrier();
  }
  // C/D layout: col = lane&15, row = (lane>>4)*4 + reg   [verified m89/m91]
#pragma unroll
  for (int mf = 0; mf < 8; ++mf)
#pragma unroll
    for (int nf = 0; nf < 4; ++nf)
#pragma unroll
      for (int rg = 0; rg < 4; ++rg) {
        const int row = m0 + wm * 128 + mf * 16 + g * 4 + rg;
        const int col = n0 + wn * 64 + nf * 16 + l15;
        if constexpr (OBF16)
          ((u16*)Cp)[(size_t)row * ldc + col] = rne16(acc[mf][nf][rg]);
        else
          ((float*)Cp)[(size_t)row * ldc + col] = acc[mf][nf][rg];
      }
}

// ============ bf16 GEMM, 2-phase 128x128 (kept for the small V GEMM) ========
template <bool OBF16>
__global__ __launch_bounds__(256) void gemm_bf16(
    const u16* __restrict__ A, const u16* __restrict__ B,
    void* __restrict__ Cp, int M, int N, int K, int lda, int ldb, int ldc) {
  __shared__ u16 As[2][128 * 32];
  __shared__ u16 Bs[2][128 * 32];
  const int tid = threadIdx.x;
  const int lane = tid & 63;
  const int w = tid >> 6;
  const int wm = w >> 1, wn = w & 1;
  int bx, by;
  xcd_swz(gridDim.x, bx, by);
  const int m0 = by * 128, n0 = bx * 128;
  const int l15 = lane & 15, g = lane >> 4;
  const int srow = tid >> 2;          // 0..63
  const int scol = (tid & 3) * 8;     // u16 units: 0,8,16,24

  const u16* ga = A + (size_t)(m0 + srow) * lda + scol;
  const u16* gb = B + (size_t)(n0 + srow) * ldb + scol;
  const size_t a64 = (size_t)64 * lda;
  const size_t b64 = (size_t)64 * ldb;

  auto stage = [&](int buf, int k0) {
    u16* lA = As[buf] + w * 512;      // 1024 B per wave
    u16* lB = Bs[buf] + w * 512;
    gload16(ga + k0, lA);             // A rows 0..63
    gload16(ga + k0 + a64, lA + 2048);// A rows 64..127
    gload16(gb + k0, lB);             // B rows 0..63
    gload16(gb + k0 + b64, lB + 2048);// B rows 64..127
  };

  f32x4 acc[4][4];
#pragma unroll
  for (int i = 0; i < 4; ++i)
#pragma unroll
    for (int j = 0; j < 4; ++j) acc[i][j] = {0.f, 0.f, 0.f, 0.f};

  stage(0, 0);
  __syncthreads();
  const int niter = K / 32;
  for (int it = 0; it < niter; ++it) {
    const int cur = it & 1;
    if (it + 1 < niter) stage(cur ^ 1, (it + 1) * 32);  // prefetch in flight
    bf16x8 af[4], bfr[4];
#pragma unroll
    for (int i = 0; i < 4; ++i)
      af[i] = *(const bf16x8*)(As[cur] + (wm * 64 + i * 16 + l15) * 32 + g * 8);
#pragma unroll
    for (int j = 0; j < 4; ++j)
      bfr[j] = *(const bf16x8*)(Bs[cur] + (wn * 64 + j * 16 + l15) * 32 + g * 8);
#pragma unroll
    for (int i = 0; i < 4; ++i)
#pragma unroll
      for (int j = 0; j < 4; ++j)
        acc[i][j] = __builtin_amdgcn_mfma_f32_16x16x32_bf16(af[i], bfr[j], acc[i][j], 0, 0, 0);
    __syncthreads();  // drains prefetch (hidden behind MFMA) + barrier
  }
#pragma unroll
  for (int i = 0; i < 4; ++i)
#pragma unroll
    for (int j = 0; j < 4; ++j)
#pragma unroll
      for (int rg = 0; rg < 4; ++rg) {
        const int row = m0 + wm * 64 + i * 16 + g * 4 + rg;
        const int col = n0 + wn * 64 + j * 16 + l15;
        if constexpr (OBF16)
          ((u16*)Cp)[(size_t)row * ldc + col] = rne16(acc[i][j][rg]);
        else
          ((float*)Cp)[(size_t)row * ldc + col] = acc[i][j][rg];
      }
}

// ============ fused 3-term split GEMM: C = Al*Bh^T + Ah*Bl^T + Ah*Bh^T ======
__global__ __launch_bounds__(256) void gemm_k3(
    const u16* __restrict__ Ahg, const u16* __restrict__ Alg,
    const u16* __restrict__ Bhg, const u16* __restrict__ Blg,
    float* __restrict__ C, int M, int N, int K) {
  __shared__ u16 Ah[2][128 * 32];
  __shared__ u16 Al[2][128 * 32];
  __shared__ u16 Bh[2][64 * 32];
  __shared__ u16 Bl[2][64 * 32];
  const int tid = threadIdx.x;
  const int lane = tid & 63;
  const int w = tid >> 6;
  const int wm = w >> 1, wn = w & 1;   // wave tile: 64(M) x 32(N)
  int bx, by;
  xcd_swz(gridDim.x, bx, by);
  const int m0 = by * 128, n0 = bx * 64;
  const int l15 = lane & 15, g = lane >> 4;
  const int srow = tid >> 2;           // 0..63
  const int scol = (tid & 3) * 8;

  const u16* gah = Ahg + (size_t)(m0 + srow) * K + scol;
  const u16* gal = Alg + (size_t)(m0 + srow) * K + scol;
  const u16* gbh = Bhg + (size_t)(n0 + srow) * K + scol;
  const u16* gbl = Blg + (size_t)(n0 + srow) * K + scol;
  const size_t a64 = (size_t)64 * K;

  auto stage = [&](int buf, int k0) {
    gload16(gah + k0, Ah[buf] + w * 512);
    gload16(gah + k0 + a64, Ah[buf] + w * 512 + 2048);
    gload16(gal + k0, Al[buf] + w * 512);
    gload16(gal + k0 + a64, Al[buf] + w * 512 + 2048);
    gload16(gbh + k0, Bh[buf] + w * 512);
    gload16(gbl + k0, Bl[buf] + w * 512);
  };

  f32x4 acc[4][2];
#pragma unroll
  for (int i = 0; i < 4; ++i)
#pragma unroll
    for (int j = 0; j < 2; ++j) acc[i][j] = {0.f, 0.f, 0.f, 0.f};

  stage(0, 0);
  __syncthreads();
  const int niter = K / 32;
  for (int it = 0; it < niter; ++it) {
    const int cur = it & 1;
    if (it + 1 < niter) stage(cur ^ 1, (it + 1) * 32);
    bf16x8 fah[4], fal[4], fbh[2], fbl[2];
#pragma unroll
    for (int i = 0; i < 4; ++i) {
      fah[i] = *(const bf16x8*)(Ah[cur] + (wm * 64 + i * 16 + l15) * 32 + g * 8);
      fal[i] = *(const bf16x8*)(Al[cur] + (wm * 64 + i * 16 + l15) * 32 + g * 8);
    }
#pragma unroll
    for (int j = 0; j < 2; ++j) {
      fbh[j] = *(const bf16x8*)(Bh[cur] + (wn * 32 + j * 16 + l15) * 32 + g * 8);
      fbl[j] = *(const bf16x8*)(Bl[cur] + (wn * 32 + j * 16 + l15) * 32 + g * 8);
    }
#pragma unroll
    for (int i = 0; i < 4; ++i)
#pragma unroll
      for (int j = 0; j < 2; ++j) {
        acc[i][j] = __builtin_amdgcn_mfma_f32_16x16x32_bf16(fal[i], fbh[j], acc[i][j], 0, 0, 0);
        acc[i][j] = __builtin_amdgcn_mfma_f32_16x16x32_bf16(fah[i], fbl[j], acc[i][j], 0, 0, 0);
        acc[i][j] = __builtin_amdgcn_mfma_f32_16x16x32_bf16(fah[i], fbh[j], acc[i][j], 0, 0, 0);
      }
    __syncthreads();
  }
#pragma unroll
  for (int i = 0; i < 4; ++i)
#pragma unroll
    for (int j = 0; j < 2; ++j)
#pragma unroll
      for (int rg = 0; rg < 4; ++rg) {
        const int row = m0 + wm * 64 + i * 16 + g * 4 + rg;
        const int col = n0 + wn * 32 + j * 16 + l15;
        C[(size_t)row * N + col] = acc[i][j][rg];
      }
}

// ---------------- XC/XD: weighted token-sums of x (exact q_mean path) -------
__global__ __launch_bounds__(128) void xcd_kernel(
    const float* __restrict__ x, const float* __restrict__ freqs,
    float* __restrict__ XC, float* __restrict__ XD) {
  const int d = blockIdx.x * 128 + threadIdx.x;
  const int i0 = blockIdx.y * 32;
  const int s0 = blockIdx.z * 128;
  float accC[32], accD[32];
#pragma unroll
  for (int ii = 0; ii < 32; ++ii) { accC[ii] = 0.f; accD[ii] = 0.f; }
  for (int s = s0; s < s0 + 128; ++s) {
    const float xv = x[(size_t)s * DIM + d];
    const float* fr = freqs + (size_t)s * 128 + i0 * 2;  // block-uniform -> s_loads
#pragma unroll
    for (int ii = 0; ii < 32; ++ii) {
      accC[ii] += fr[2 * ii] * xv;
      accD[ii] += fr[2 * ii + 1] * xv;
    }
  }
#pragma unroll
  for (int ii = 0; ii < 32; ++ii) {
    atomicAdd(&XC[(size_t)(i0 + ii) * DIM + d], accC[ii]);
    atomicAdd(&XD[(size_t)(i0 + ii) * DIM + d], accD[ii]);
  }
}

// ---------------- M1/M2: per-q-row dots with XC/XD --------------------------
__global__ __launch_bounds__(256) void mrow_kernel(
    const float* __restrict__ wq, const float* __restrict__ XC,
    const float* __restrict__ XD, float* __restrict__ M1, float* __restrict__ M2) {
  const int r = blockIdx.x * 4 + (threadIdx.x >> 6);
  const int lane = threadIdx.x & 63;
  const int i = (r & 127) >> 1;
  const float* wr = wq + (size_t)r * DIM;
  const float* xc = XC + (size_t)i * DIM;
  const float* xd = XD + (size_t)i * DIM;
  float s1 = 0.f, s2 = 0.f;
  for (int k = lane; k < DIM; k += 64) {
    float wv = wr[k];
    s1 += wv * xc[k];
    s2 += wv * xd[k];
  }
#pragma unroll
  for (int off = 1; off < 64; off <<= 1) {
    s1 += __shfl_xor(s1, off, 64);
    s2 += __shfl_xor(s2, off, 64);
  }
  if (lane == 0) { M1[r] = s1; M2[r] = s2; }
}

// ---------------- RoPE on Q (bf16 in, bf16 out) -----------------------------
__global__ __launch_bounds__(256) void rope_q_kernel(
    const u16* __restrict__ qvb, const float* __restrict__ freqs,
    u16* __restrict__ qb) {
  const int h = blockIdx.y;
  const int s0 = blockIdx.x * 64;
  const int tid = threadIdx.x;
  const int d = tid & 127, half = tid >> 7;
  for (int pp = half; pp < 64; pp += 2) {
    const int s = s0 + pp;
    u32 pr = *(const u32*)(qvb + (size_t)s * QVW + h * D + (d & ~1));
    float a = bflo(pr), b = bfhi(pr);
    float2 fc = *(const float2*)(freqs + (size_t)s * 128 + (d & ~1));
    float o = (d & 1) ? (b * fc.x + a * fc.y) : (a * fc.x - b * fc.y);
    qb[((size_t)h * S + s) * D + d] = rne16(o);
  }
}

// ---------------- RoPE on precise K + block means; V cast + transpose -------
__global__ __launch_bounds__(128) void rope_kv_kernel(
    const float* __restrict__ kf, const u16* __restrict__ qvb,
    const float* __restrict__ freqs,
    u16* __restrict__ kb, u16* __restrict__ vbt, float* __restrict__ krep) {
  const int hl = blockIdx.y;
  const int t = blockIdx.x;  // token block 0..511
  const int d = threadIdx.x;
  float sum = 0.f;
  u16 vv[8];
#pragma unroll
  for (int pp = 0; pp < 8; ++pp) {
    const int s = t * 8 + pp;
    float2 kp = *(const float2*)(kf + (size_t)s * 1024 + hl * D + (d & ~1));
    float2 fc = *(const float2*)(freqs + (size_t)s * 128 + (d & ~1));
    float o = (d & 1) ? (kp.y * fc.x + kp.x * fc.y) : (kp.x * fc.x - kp.y * fc.y);
    kb[((size_t)hl * S + s) * D + d] = rne16(o);
    sum += o;
    vv[pp] = qvb[(size_t)s * QVW + H * D + hl * D + d];  // V at packed col 4096+
  }
  krep[((size_t)t * HL + hl) * D + d] = sum * 0.125f;
  uint4 pk;
  pk.x = pk2(vv[0], vv[1]);
  pk.y = pk2(vv[2], vv[3]);
  pk.z = pk2(vv[4], vv[5]);
  pk.w = pk2(vv[6], vv[7]);
  *(uint4*)(vbt + ((size_t)hl * D + d) * S + t * 8) = pk;
}

// ---------------- scores + top-100 selection per head -----------------------
__global__ __launch_bounds__(512) void topk_kernel(
    const float* __restrict__ M1, const float* __restrict__ M2,
    const float* __restrict__ krep, int* __restrict__ bidx) {
  const int h = blockIdx.x;
  const int t = threadIdx.x;  // block id 0..511
  __shared__ float qm[128];
  if (t < 128) {
    int r = h * 128 + t;
    float v = (t & 1) ? (M1[r] + M2[r - 1]) : (M1[r] - M2[r + 1]);
    qm[t] = v * (1.f / 4096.f);
  }
  __syncthreads();
  const float* kr = krep + ((size_t)t * HL + (h >> 2)) * 128;
  float s = 0.f;
#pragma unroll 8
  for (int d = 0; d < 128; ++d) s += qm[d] * kr[d];
  s *= SCALE;
  if (t < 4 || t >= 508) s = NEGF;  // sink + window masked out of top-k
  if (t < 4) {
    bidx[h * KL + t] = t;            // sink blocks 0..3
    bidx[h * KL + 4 + t] = 508 + t;  // window blocks 508..511
  }
  __shared__ float wv[8];
  __shared__ int wi[8];
  __shared__ int bestsh;
  for (int iter = 0; iter < 100; ++iter) {
    float v = s;
    int idx = t;
#pragma unroll
    for (int off = 1; off < 64; off <<= 1) {
      float ov = __shfl_xor(v, off, 64);
      int oi = __shfl_xor(idx, off, 64);
      if (ov > v || (ov == v && oi < idx)) { v = ov; idx = oi; }
    }
    if ((t & 63) == 0) { wv[t >> 6] = v; wi[t >> 6] = idx; }
    __syncthreads();
    if (t == 0) {
      float bv = wv[0];
      int bi = wi[0];
#pragma unroll
      for (int u = 1; u < 8; ++u)
        if (wv[u] > bv || (wv[u] == bv && wi[u] < bi)) { bv = wv[u]; bi = wi[u]; }
      bestsh = bi;
      bidx[h * KL + 8 + iter] = bi;
    }
    __syncthreads();
    if (t == bestsh) s = NEGF;
  }
}

// ---------------- MFMA flash attention over selected blocks -----------------
__global__ __launch_bounds__(256) void attn_mfma(
    const u16* __restrict__ qb, const u16* __restrict__ kb,
    const u16* __restrict__ vbt, const int* __restrict__ bidx,
    u16* __restrict__ attno) {
  __shared__ u16 Ks[32][136];   // 32 toks x 128 d (+8 pad)
  __shared__ u16 Vt[128][40];   // 128 d x 32 toks (+8 pad)
  __shared__ u16 Ps[4][16][40]; // per wave: 16 rows x 32 toks (+8 pad)
  const int h = blockIdx.y, hl = h >> 2;
  const int q0 = blockIdx.x * 64;
  const int tid = threadIdx.x;
  const int w = tid >> 6, lane = tid & 63;
  const int l15 = lane & 15, g = lane >> 4;

  bf16x8 qf[4];
  {
    const u16* qp = qb + ((size_t)h * S + q0 + w * 16 + l15) * D + g * 8;
#pragma unroll
    for (int c = 0; c < 4; ++c) qf[c] = *(const bf16x8*)(qp + c * 32);
  }
  f32x4 o[8];
#pragma unroll
  for (int c = 0; c < 8; ++c) o[c] = {0.f, 0.f, 0.f, 0.f};
  float mrow[4], lrow[4];
#pragma unroll
  for (int r = 0; r < 4; ++r) { mrow[r] = NEGF; lrow[r] = 0.f; }

  for (int step = 0; step < KL / 4; ++step) {
    const int b0 = bidx[h * KL + step * 4 + 0];
    const int b1 = bidx[h * KL + step * 4 + 1];
    const int b2 = bidx[h * KL + step * 4 + 2];
    const int b3 = bidx[h * KL + step * 4 + 3];
    {  // stage K: tok = tid>>3, seg = tid&7 (32B contiguous per thread)
      const int tok = tid >> 3, seg = tid & 7;
      const int blk = (tok < 8) ? b0 : (tok < 16) ? b1 : (tok < 24) ? b2 : b3;
      const u16* src = kb + ((size_t)hl * S + blk * 8 + (tok & 7)) * D + seg * 16;
      *(uint4*)&Ks[tok][seg * 16] = *(const uint4*)src;
      *(uint4*)&Ks[tok][seg * 16 + 8] = *(const uint4*)(src + 8);
    }
    {  // stage V^T: d = tid>>1, half = tid&1 (two 8-token runs)
      const int d = tid >> 1, hf = tid & 1;
      const int ba = hf ? b2 : b0, bb = hf ? b3 : b1;
      const u16* src = vbt + ((size_t)hl * D + d) * S;
      *(uint4*)&Vt[d][hf * 16] = *(const uint4*)(src + ba * 8);
      *(uint4*)&Vt[d][hf * 16 + 8] = *(const uint4*)(src + bb * 8);
    }
    __syncthreads();
    // QK^T: two 16x16 tiles (toks 0..15, 16..31)
    f32x4 sA = {0.f, 0.f, 0.f, 0.f}, sB = {0.f, 0.f, 0.f, 0.f};
#pragma unroll
    for (int c = 0; c < 4; ++c) {
      bf16x8 k0 = *(const bf16x8*)&Ks[l15][c * 32 + g * 8];
      bf16x8 k1 = *(const bf16x8*)&Ks[16 + l15][c * 32 + g * 8];
      sA = __builtin_amdgcn_mfma_f32_16x16x32_bf16(qf[c], k0, sA, 0, 0, 0);
      sB = __builtin_amdgcn_mfma_f32_16x16x32_bf16(qf[c], k1, sB, 0, 0, 0);
    }
    const int tgA = ((l15 < 8) ? b0 : b1) * 8 + (l15 & 7);
    const int tgB = ((l15 < 8) ? b2 : b3) * 8 + (l15 & 7);
    float pA[4], pB[4], alpha[4];
#pragma unroll
    for (int r = 0; r < 4; ++r) {
      const int sq = q0 + w * 16 + g * 4 + r;
      pA[r] = (tgA <= sq) ? sA[r] * SCALE : NEGF;
      pB[r] = (tgB <= sq) ? sB[r] * SCALE : NEGF;
      float mx = fmaxf(pA[r], pB[r]);
      mx = fmaxf(mx, __shfl_xor(mx, 1, 64));
      mx = fmaxf(mx, __shfl_xor(mx, 2, 64));
      mx = fmaxf(mx, __shfl_xor(mx, 4, 64));
      mx = fmaxf(mx, __shfl_xor(mx, 8, 64));
      const float mnew = fmaxf(mrow[r], mx);
      alpha[r] = __expf(mrow[r] - mnew);
      mrow[r] = mnew;
      pA[r] = __expf(pA[r] - mnew);
      pB[r] = __expf(pB[r] - mnew);
      float rs = pA[r] + pB[r];
      rs += __shfl_xor(rs, 1, 64);
      rs += __shfl_xor(rs, 2, 64);
      rs += __shfl_xor(rs, 4, 64);
      rs += __shfl_xor(rs, 8, 64);
      lrow[r] = lrow[r] * alpha[r] + rs;
    }
#pragma unroll
    for (int c = 0; c < 8; ++c) {
      o[c][0] *= alpha[0]; o[c][1] *= alpha[1];
      o[c][2] *= alpha[2]; o[c][3] *= alpha[3];
    }
    // P: C-layout -> LDS -> A-layout (within-wave, in-order LDS)
#pragma unroll
    for (int r = 0; r < 4; ++r) {
      Ps[w][g * 4 + r][l15] = rne16(pA[r]);
      Ps[w][g * 4 + r][16 + l15] = rne16(pB[r]);
    }
    bf16x8 pf = *(const bf16x8*)&Ps[w][l15][g * 8];
#pragma unroll
    for (int c = 0; c < 8; ++c) {
      bf16x8 vf = *(const bf16x8*)&Vt[c * 16 + l15][g * 8];
      o[c] = __builtin_amdgcn_mfma_f32_16x16x32_bf16(pf, vf, o[c], 0, 0, 0);
    }
    __syncthreads();
  }
  float inv[4];
#pragma unroll
  for (int r = 0; r < 4; ++r) inv[r] = 1.f / lrow[r];
#pragma unroll
  for (int c = 0; c < 8; ++c)
#pragma unroll
    for (int r = 0; r < 4; ++r)
      attno[(size_t)(q0 + w * 16 + g * 4 + r) * DIM + h * D + c * 16 + l15] =
          rne16(o[c][r] * inv[r]);
}

extern "C" void kernel_launch(void* const* d_in, const int* in_sizes, int n_in,
                              void* d_out, int out_size, void* d_ws, size_t ws_size,
                              hipStream_t stream) {
  const float* x     = (const float*)d_in[0];  // (1,4096,4096)
  const float* freqs = (const float*)d_in[1];  // (4096,64,2)
  const float* wqkv  = (const float*)d_in[2];  // (6144,4096)
  const float* wo    = (const float*)d_in[3];  // (4096,4096)
  float* out = (float*)d_out;                  // (1,4096,4096) f32

  char* p = (char*)d_ws;
  auto alloc = [&](size_t bytes) {
    char* r = p;
    p += (bytes + 255) & ~(size_t)255;
    return r;
  };
  u16*   xh   = (u16*)alloc((size_t)S * DIM * 2);        // 32 MB x hi (rne bf16)
  u16*   xl   = (u16*)alloc((size_t)S * DIM * 2);        // 32 MB x lo residual
  u16*   wqv  = (u16*)alloc((size_t)QVW * DIM * 2);      // 40 MB packed [Q|V] bf16
  u16*   wkh  = (u16*)alloc((size_t)HL * D * DIM * 2);   //  8 MB K-head hi
  u16*   wkl  = (u16*)alloc((size_t)HL * D * DIM * 2);   //  8 MB K-head lo
  u16*   wob  = (u16*)alloc((size_t)DIM * DIM * 2);      // 32 MB wo bf16
  u16*   qvb  = (u16*)alloc((size_t)S * QVW * 2);        // 40 MB bf16 [Q|V]
  float* kf32 = (float*)alloc((size_t)S * HL * D * 4);   // 16 MB precise k
  u16*   qb   = (u16*)alloc((size_t)H * S * D * 2);      // 32 MB (H,S,D)
  u16*   kb   = (u16*)alloc((size_t)HL * S * D * 2);     //  8 MB (HL,S,D)
  u16*   vbt  = (u16*)alloc((size_t)HL * D * S * 2);     //  8 MB (HL,D,S)
  float* krep = (float*)alloc((size_t)TB * HL * D * 4);  //  2 MB
  float* XC   = (float*)alloc((size_t)64 * DIM * 4);     //  1 MB
  float* XD   = (float*)alloc((size_t)64 * DIM * 4);     //  1 MB
  float* M1   = (float*)alloc((size_t)H * D * 4);
  float* M2   = (float*)alloc((size_t)H * D * 4);
  int*   bidx = (int*)alloc((size_t)H * KL * 4);
  u16*   attno = (u16*)alloc((size_t)S * DIM * 2);       // 32 MB

  hipMemsetAsync(XC, 0, (size_t)64 * DIM * 4, stream);
  hipMemsetAsync(XD, 0, (size_t)64 * DIM * 4, stream);

  // ---- conversion passes (memory-bound) ----
  split_f32_kernel<<<(S * DIM) / 2048, 256, 0, stream>>>(x, xh, xl);
  conv_wqkv_kernel<<<(NQKV * DIM) / 2048, 256, 0, stream>>>(wqkv, wqv, wkh, wkl);
  cast_bf16_kernel<<<(DIM * DIM) / 2048, 256, 0, stream>>>(wo, wob);

  // ---- bf16 Q (8-phase 256^2; grid 256 = 1 block/CU) ----
  gemm256<true><<<dim3((H * D) / 256, S / 256), 512, 0, stream>>>(
      xh, wqv, qvb, S, H * D, DIM, DIM, DIM, QVW);
  // ---- bf16 V (2-phase 128^2; N=1024, grid 256) ----
  gemm_bf16<true><<<dim3((HL * D) / 128, S / 128), 256, 0, stream>>>(
      xh, wqv + (size_t)(H * D) * DIM, qvb + H * D, S, HL * D, DIM, DIM, DIM, QVW);

  // ---- precise K heads: fused (Al*Bh + Ah*Bl + Ah*Bh), single pass ----
  gemm_k3<<<dim3((HL * D) / 64, S / 128), 256, 0, stream>>>(
      xh, xl, wkh, wkl, kf32, S, HL * D, DIM);

  // ---- exact q_mean via rope linearity (f32 inputs, unchanged) ----
  xcd_kernel<<<dim3(32, 2, 32), 128, 0, stream>>>(x, freqs, XC, XD);
  mrow_kernel<<<1024, 256, 0, stream>>>(wqkv, XC, XD, M1, M2);
  rope_q_kernel<<<dim3(S / 64, H), 256, 0, stream>>>(qvb, freqs, qb);
  rope_kv_kernel<<<dim3(TB, HL), 128, 0, stream>>>(kf32, qvb, freqs, kb, vbt, krep);
  topk_kernel<<<H, 512, 0, stream>>>(M1, M2, krep, bidx);
  attn_mfma<<<dim3(S / 64, H), 256, 0, stream>>>(qb, kb, vbt, bidx, attno);
  // ---- output projection (8-phase 256^2; grid 256) ----
  gemm256<false><<<dim3(DIM / 256, S / 256), 512, 0, stream>>>(
      attno, wob, out, S, DIM, DIM, DIM, DIM, DIM);
}